// Round 1
// baseline (958.174 us; speedup 1.0000x reference)
//
#include <hip/hip_runtime.h>

typedef float f32x4 __attribute__((ext_vector_type(4)));
typedef __bf16 bf16x8 __attribute__((ext_vector_type(8)));
typedef unsigned short u16;
typedef unsigned short u16x4 __attribute__((ext_vector_type(4)));
typedef unsigned short u16x8 __attribute__((ext_vector_type(8)));
typedef unsigned int u32;

#define SEQ 1024
#define NBATCH 4
#define DM 1024
#define HD 4096
#define NV 32000
#define NT (SEQ * NBATCH)

__device__ __forceinline__ u16 f2bf(float f) {
  u32 u = __builtin_bit_cast(u32, f);
  return (u16)((u + 0x7FFFu + ((u >> 16) & 1u)) >> 16);  // RTNE
}

// ---------------- f32 -> bf16 cast, 8 elems/thread ----------------
__global__ __launch_bounds__(256) void cast_bf16_kernel(const float* __restrict__ in,
                                                        u16* __restrict__ out, int n8) {
  int i = blockIdx.x * 256 + threadIdx.x;
  if (i >= n8) return;
  const f32x4* p = (const f32x4*)(in + (long)i * 8);
  f32x4 a = p[0], b = p[1];
  u16x8 o;
  o[0] = f2bf(a[0]); o[1] = f2bf(a[1]); o[2] = f2bf(a[2]); o[3] = f2bf(a[3]);
  o[4] = f2bf(b[0]); o[5] = f2bf(b[1]); o[6] = f2bf(b[2]); o[7] = f2bf(b[3]);
  *(u16x8*)(out + (long)i * 8) = o;
}

// ---------------- embedding gather: f32 + bf16 copies ----------------
__global__ __launch_bounds__(256) void embed_kernel(const int* __restrict__ ids,
                                                    const float* __restrict__ tab,
                                                    float* __restrict__ ef,
                                                    u16* __restrict__ eh) {
  int t = blockIdx.x, tid = threadIdx.x;
  long id = ids[t];
  f32x4 v = *(const f32x4*)(tab + id * DM + tid * 4);
  *(f32x4*)(ef + (long)t * DM + tid * 4) = v;
  u16x4 h;
  h[0] = f2bf(v[0]); h[1] = f2bf(v[1]); h[2] = f2bf(v[2]); h[3] = f2bf(v[3]);
  *(u16x4*)(eh + (long)t * DM + tid * 4) = h;
}

// ---------------- row softmax (1024 cols), scale 1/32, bf16 out ----------------
__global__ __launch_bounds__(256) void softmax_kernel(const float* __restrict__ s,
                                                      u16* __restrict__ p) {
  int row = blockIdx.x, tid = threadIdx.x;
  const float* rp = s + (long)row * SEQ;
  f32x4 v = *(const f32x4*)(rp + tid * 4);
  float mx = fmaxf(fmaxf(v[0], v[1]), fmaxf(v[2], v[3]));
  for (int o = 32; o; o >>= 1) mx = fmaxf(mx, __shfl_xor(mx, o));
  __shared__ float red[4];
  if ((tid & 63) == 0) red[tid >> 6] = mx;
  __syncthreads();
  mx = fmaxf(fmaxf(red[0], red[1]), fmaxf(red[2], red[3]));
  const float sc = 0.03125f;  // 1/sqrt(1024)
  f32x4 e;
  e[0] = expf((v[0] - mx) * sc); e[1] = expf((v[1] - mx) * sc);
  e[2] = expf((v[2] - mx) * sc); e[3] = expf((v[3] - mx) * sc);
  float sm = e[0] + e[1] + e[2] + e[3];
  for (int o = 32; o; o >>= 1) sm += __shfl_xor(sm, o);
  __syncthreads();
  if ((tid & 63) == 0) red[tid >> 6] = sm;
  __syncthreads();
  sm = red[0] + red[1] + red[2] + red[3];
  float inv = 1.0f / sm;
  u16x4 o4;
  o4[0] = f2bf(e[0] * inv); o4[1] = f2bf(e[1] * inv);
  o4[2] = f2bf(e[2] * inv); o4[3] = f2bf(e[3] * inv);
  *(u16x4*)(p + (long)row * SEQ + tid * 4) = o4;
}

// ---------------- LayerNorm over D=1024; optional f32 and bf16 outputs ----------------
__global__ __launch_bounds__(256) void ln_kernel(const float* __restrict__ in,
                                                 const float* __restrict__ g,
                                                 const float* __restrict__ be,
                                                 float* __restrict__ outf,
                                                 u16* __restrict__ outh) {
  int row = blockIdx.x, tid = threadIdx.x;
  f32x4 v = *(const f32x4*)(in + (long)row * DM + tid * 4);
  float s = v[0] + v[1] + v[2] + v[3];
  float q = v[0] * v[0] + v[1] * v[1] + v[2] * v[2] + v[3] * v[3];
  for (int o = 32; o; o >>= 1) { s += __shfl_xor(s, o); q += __shfl_xor(q, o); }
  __shared__ float rs_[4], rq_[4];
  if ((tid & 63) == 0) { rs_[tid >> 6] = s; rq_[tid >> 6] = q; }
  __syncthreads();
  s = rs_[0] + rs_[1] + rs_[2] + rs_[3];
  q = rq_[0] + rq_[1] + rq_[2] + rq_[3];
  float mean = s * (1.0f / DM);
  float var = q * (1.0f / DM) - mean * mean;
  float rstd = rsqrtf(var + 1e-5f);
  f32x4 gg = *(const f32x4*)(g + tid * 4);
  f32x4 bb = *(const f32x4*)(be + tid * 4);
  f32x4 y;
  y[0] = (v[0] - mean) * rstd * gg[0] + bb[0];
  y[1] = (v[1] - mean) * rstd * gg[1] + bb[1];
  y[2] = (v[2] - mean) * rstd * gg[2] + bb[2];
  y[3] = (v[3] - mean) * rstd * gg[3] + bb[3];
  if (outf) *(f32x4*)(outf + (long)row * DM + tid * 4) = y;
  if (outh) {
    u16x4 h;
    h[0] = f2bf(y[0]); h[1] = f2bf(y[1]); h[2] = f2bf(y[2]); h[3] = f2bf(y[3]);
    *(u16x4*)(outh + (long)row * DM + tid * 4) = h;
  }
}

// ---------------- generic bf16 GEMM: C = A (MxK) * B^T (B is NxK row-major) ----------------
// m97 structure: 128x128 tile, BK=32, 4 waves 2x2, mfma 16x16x32 bf16, global_load_lds(16B).
#define BM 128
#define BN 128
#define BK 32

#define GLD(gp, lp)                                              \
  __builtin_amdgcn_global_load_lds(                              \
      (__attribute__((address_space(1))) void*)(gp),             \
      (__attribute__((address_space(3))) void*)(lp), 16, 0, 0)

__global__ __launch_bounds__(256) void gemm_bt(
    const u16* __restrict__ A, const u16* __restrict__ B,
    float* __restrict__ Cf, u16* __restrict__ Ch,
    const float* __restrict__ bias, const float* __restrict__ resid,
    int K, int lda, int ldb, int ldc,
    long batA, long batB, long batC, int relu) {
  __shared__ u16 As[BM * BK];
  __shared__ u16 Bs[BN * BK];
  const int tid = threadIdx.x;
  const int bz = blockIdx.z;
  A += (long)bz * batA;
  B += (long)bz * batB;
  const long cbase = (long)bz * batC;
  const int row0 = blockIdx.y * BM;
  const int col0 = blockIdx.x * BN;
  const int l = tid & 63;
  const int w = tid >> 6;
  const int wr = (w >> 1) * 64, wc = (w & 1) * 64;

  f32x4 acc[4][4] = {};

  // staging: chunk c (16B = 8 bf16): row = c>>2, col = (c&3)*8. chunks tid and tid+256.
  const u16* gA = A + (long)(row0 + (tid >> 2)) * lda + (tid & 3) * 8;
  const u16* gB = B + (long)(col0 + (tid >> 2)) * ldb + (tid & 3) * 8;
  const long a64 = (long)64 * lda, b64 = (long)64 * ldb;
  u16* lA = As + tid * 8;
  u16* lB = Bs + tid * 8;

  // MFMA fragment read addresses: lane l -> row (l&15), k (l>>4)*8..+8 (contiguous)
  const int fr = l & 15;
  const int fk = (l >> 4) * 8;
  const u16* rA = As + (wr + fr) * BK + fk;
  const u16* rB = Bs + (wc + fr) * BK + fk;

  for (int k0 = 0; k0 < K; k0 += BK) {
    GLD(gA + k0, lA);
    GLD(gA + a64 + k0, lA + 2048);
    GLD(gB + k0, lB);
    GLD(gB + b64 + k0, lB + 2048);
    __syncthreads();  // drains vmcnt before barrier (compiler-emitted)
    bf16x8 af[4], bf[4];
#pragma unroll
    for (int m = 0; m < 4; ++m) af[m] = *(const bf16x8*)(rA + m * 16 * BK);
#pragma unroll
    for (int n = 0; n < 4; ++n) bf[n] = *(const bf16x8*)(rB + n * 16 * BK);
#pragma unroll
    for (int m = 0; m < 4; ++m)
#pragma unroll
      for (int n = 0; n < 4; ++n)
        acc[m][n] = __builtin_amdgcn_mfma_f32_16x16x32_bf16(af[m], bf[n], acc[m][n], 0, 0, 0);
    __syncthreads();
  }

  // epilogue: C/D layout col = lane&15, row = (lane>>4)*4 + reg
  const int er = row0 + wr + ((l >> 4) << 2);
  const int ec = col0 + wc + (l & 15);
#pragma unroll
  for (int m = 0; m < 4; ++m) {
#pragma unroll
    for (int n = 0; n < 4; ++n) {
      f32x4 v = acc[m][n];
      const int c = ec + n * 16;
      float bv = bias ? bias[c] : 0.0f;
#pragma unroll
      for (int i = 0; i < 4; ++i) {
        const int r = er + m * 16 + i;
        float x = v[i] + bv;
        if (resid) x += resid[(long)r * ldc + c];
        if (relu) x = fmaxf(x, 0.0f);
        if (Cf) Cf[cbase + (long)r * ldc + c] = x;
        if (Ch) Ch[cbase + (long)r * ldc + c] = f2bf(x);
      }
    }
  }
}

extern "C" void kernel_launch(void* const* d_in, const int* in_sizes, int n_in,
                              void* d_out, int out_size, void* d_ws, size_t ws_size,
                              hipStream_t stream) {
  const int* ids = (const int*)d_in[0];
  const float* tab = (const float*)d_in[1];
  const float* WQ = (const float*)d_in[2];
  const float* WK = (const float*)d_in[3];
  const float* WV = (const float*)d_in[4];
  const float* Wo = (const float*)d_in[5];
  const float* bo = (const float*)d_in[6];
  const float* W1 = (const float*)d_in[7];
  const float* b1 = (const float*)d_in[8];
  const float* W2 = (const float*)d_in[9];
  const float* b2 = (const float*)d_in[10];
  const float* g1 = (const float*)d_in[11];
  const float* be1 = (const float*)d_in[12];
  const float* g2 = (const float*)d_in[13];
  const float* be2 = (const float*)d_in[14];
  const float* Wd = (const float*)d_in[15];
  const float* bd = (const float*)d_in[16];
  float* logits = (float*)d_out;

  if (ws_size < 280000000ull) return;  // need ~276 MB scratch

  char* p = (char*)d_ws;
  auto alloc = [&](size_t bytes) {
    char* r = p;
    p += (bytes + 255) & ~(size_t)255;
    return r;
  };
  float* embf = (float*)alloc((size_t)NT * DM * 4);
  u16* embh = (u16*)alloc((size_t)NT * DM * 2);
  u16* WQh = (u16*)alloc((size_t)DM * DM * 2);
  u16* WKh = (u16*)alloc((size_t)DM * DM * 2);
  u16* WVh = (u16*)alloc((size_t)DM * DM * 2);
  u16* Woh = (u16*)alloc((size_t)DM * DM * 2);
  u16* W1h = (u16*)alloc((size_t)HD * DM * 2);
  u16* W2h = (u16*)alloc((size_t)DM * HD * 2);
  u16* Wdh = (u16*)alloc((size_t)NV * DM * 2);
  u16* Qh = (u16*)alloc((size_t)NT * DM * 2);
  u16* Kh = (u16*)alloc((size_t)NT * DM * 2);
  u16* VTh = (u16*)alloc((size_t)NBATCH * DM * SEQ * 2);
  float* scoresf = (float*)alloc((size_t)NBATCH * SEQ * SEQ * 4);
  u16* Ph = (u16*)alloc((size_t)NBATCH * SEQ * SEQ * 2);
  u16* zh = (u16*)alloc((size_t)NT * DM * 2);
  float* r1f = (float*)alloc((size_t)NT * DM * 4);
  float* xf = (float*)alloc((size_t)NT * DM * 4);
  u16* xh = (u16*)alloc((size_t)NT * DM * 2);
  u16* hh = (u16*)alloc((size_t)NT * HD * 2);
  float* r2f = (float*)alloc((size_t)NT * DM * 4);
  u16* outh = (u16*)alloc((size_t)NT * DM * 2);

  // --- weight casts to bf16 ---
  cast_bf16_kernel<<<dim3(DM * DM / 8 / 256), 256, 0, stream>>>(WQ, WQh, DM * DM / 8);
  cast_bf16_kernel<<<dim3(DM * DM / 8 / 256), 256, 0, stream>>>(WK, WKh, DM * DM / 8);
  cast_bf16_kernel<<<dim3(DM * DM / 8 / 256), 256, 0, stream>>>(WV, WVh, DM * DM / 8);
  cast_bf16_kernel<<<dim3(DM * DM / 8 / 256), 256, 0, stream>>>(Wo, Woh, DM * DM / 8);
  cast_bf16_kernel<<<dim3(HD * DM / 8 / 256), 256, 0, stream>>>(W1, W1h, HD * DM / 8);
  cast_bf16_kernel<<<dim3(DM * HD / 8 / 256), 256, 0, stream>>>(W2, W2h, DM * HD / 8);
  cast_bf16_kernel<<<dim3(NV * DM / 8 / 256), 256, 0, stream>>>(Wd, Wdh, NV * DM / 8);

  // --- embedding ---
  embed_kernel<<<NT, 256, 0, stream>>>(ids, tab, embf, embh);

  // --- Q, K projections (token layout [NT, DM]) ---
  gemm_bt<<<dim3(DM / BN, NT / BM, 1), 256, 0, stream>>>(
      embh, WQh, nullptr, Qh, nullptr, nullptr, DM, DM, DM, DM, 0, 0, 0, 0);
  gemm_bt<<<dim3(DM / BN, NT / BM, 1), 256, 0, stream>>>(
      embh, WKh, nullptr, Kh, nullptr, nullptr, DM, DM, DM, DM, 0, 0, 0, 0);

  // --- V^T per batch: VT[b][e][s] = sum_d WV[e,d] * emb[s,b,d] ---
  gemm_bt<<<dim3(SEQ / BN, DM / BM, NBATCH), 256, 0, stream>>>(
      WVh, embh, nullptr, VTh, nullptr, nullptr, DM, DM, NBATCH * DM, SEQ,
      0, DM, (long)DM * SEQ, 0);

  // --- scores[b][q][k] = Q_b . K_b (scale folded into softmax) ---
  gemm_bt<<<dim3(SEQ / BN, SEQ / BM, NBATCH), 256, 0, stream>>>(
      Qh, Kh, scoresf, nullptr, nullptr, nullptr, DM, NBATCH * DM, NBATCH * DM, SEQ,
      DM, DM, (long)SEQ * SEQ, 0);

  softmax_kernel<<<NBATCH * SEQ, 256, 0, stream>>>(scoresf, Ph);

  // --- Z[b][q][d] = sum_k P[b,q,k] * VT[b,d,k], written to token layout zh ---
  gemm_bt<<<dim3(DM / BN, SEQ / BM, NBATCH), 256, 0, stream>>>(
      Ph, VTh, nullptr, zh, nullptr, nullptr, SEQ, SEQ, SEQ, NBATCH * DM,
      (long)SEQ * SEQ, (long)DM * SEQ, DM, 0);

  // --- r1 = z @ Wo^T + bo + emb ---
  gemm_bt<<<dim3(DM / BN, NT / BM, 1), 256, 0, stream>>>(
      zh, Woh, r1f, nullptr, bo, embf, DM, DM, DM, DM, 0, 0, 0, 0);

  ln_kernel<<<NT, 256, 0, stream>>>(r1f, g1, be1, xf, xh);

  // --- FFN ---
  gemm_bt<<<dim3(HD / BN, NT / BM, 1), 256, 0, stream>>>(
      xh, W1h, nullptr, hh, b1, nullptr, DM, DM, DM, HD, 0, 0, 0, 1);
  gemm_bt<<<dim3(DM / BN, NT / BM, 1), 256, 0, stream>>>(
      hh, W2h, r2f, nullptr, b2, xf, HD, HD, HD, DM, 0, 0, 0, 0);

  ln_kernel<<<NT, 256, 0, stream>>>(r2f, g2, be2, nullptr, outh);

  // --- logits = out @ Wd^T + bd ---
  gemm_bt<<<dim3(NV / BN, NT / BM, 1), 256, 0, stream>>>(
      outh, Wdh, logits, nullptr, bd, nullptr, DM, DM, DM, NV, 0, 0, 0, 0);
}

// Round 3
// 928.812 us; speedup vs baseline: 1.0316x; 1.0316x over previous
//
#include <hip/hip_runtime.h>

typedef float f32x4 __attribute__((ext_vector_type(4)));
typedef __bf16 bf16x8 __attribute__((ext_vector_type(8)));
typedef unsigned short u16;
typedef unsigned short u16x4 __attribute__((ext_vector_type(4)));
typedef unsigned short u16x8 __attribute__((ext_vector_type(8)));
typedef unsigned int u32;

#define SEQ 1024
#define NBATCH 4
#define DM 1024
#define HD 4096
#define NV 32000
#define NT (SEQ * NBATCH)

__device__ __forceinline__ u16 f2bf(float f) {
  u32 u = __builtin_bit_cast(u32, f);
  return (u16)((u + 0x7FFFu + ((u >> 16) & 1u)) >> 16);  // RTNE
}

// ---------------- f32 -> bf16 cast, 8 elems/thread ----------------
__global__ __launch_bounds__(256) void cast_bf16_kernel(const float* __restrict__ in,
                                                        u16* __restrict__ out, int n8) {
  int i = blockIdx.x * 256 + threadIdx.x;
  if (i >= n8) return;
  const f32x4* p = (const f32x4*)(in + (long)i * 8);
  f32x4 a = p[0], b = p[1];
  u16x8 o;
  o[0] = f2bf(a[0]); o[1] = f2bf(a[1]); o[2] = f2bf(a[2]); o[3] = f2bf(a[3]);
  o[4] = f2bf(b[0]); o[5] = f2bf(b[1]); o[6] = f2bf(b[2]); o[7] = f2bf(b[3]);
  *(u16x8*)(out + (long)i * 8) = o;
}

// ---------------- embedding gather: f32 + bf16 copies ----------------
__global__ __launch_bounds__(256) void embed_kernel(const int* __restrict__ ids,
                                                    const float* __restrict__ tab,
                                                    float* __restrict__ ef,
                                                    u16* __restrict__ eh) {
  int t = blockIdx.x, tid = threadIdx.x;
  long id = ids[t];
  f32x4 v = *(const f32x4*)(tab + id * DM + tid * 4);
  *(f32x4*)(ef + (long)t * DM + tid * 4) = v;
  u16x4 h;
  h[0] = f2bf(v[0]); h[1] = f2bf(v[1]); h[2] = f2bf(v[2]); h[3] = f2bf(v[3]);
  *(u16x4*)(eh + (long)t * DM + tid * 4) = h;
}

// ---------------- row softmax (1024 cols), scale 1/32, bf16 out ----------------
__global__ __launch_bounds__(256) void softmax_kernel(const float* __restrict__ s,
                                                      u16* __restrict__ p) {
  int row = blockIdx.x, tid = threadIdx.x;
  const float* rp = s + (long)row * SEQ;
  f32x4 v = *(const f32x4*)(rp + tid * 4);
  float mx = fmaxf(fmaxf(v[0], v[1]), fmaxf(v[2], v[3]));
  for (int o = 32; o; o >>= 1) mx = fmaxf(mx, __shfl_xor(mx, o));
  __shared__ float red[4];
  if ((tid & 63) == 0) red[tid >> 6] = mx;
  __syncthreads();
  mx = fmaxf(fmaxf(red[0], red[1]), fmaxf(red[2], red[3]));
  const float sc = 0.03125f;  // 1/sqrt(1024)
  f32x4 e;
  e[0] = expf((v[0] - mx) * sc); e[1] = expf((v[1] - mx) * sc);
  e[2] = expf((v[2] - mx) * sc); e[3] = expf((v[3] - mx) * sc);
  float sm = e[0] + e[1] + e[2] + e[3];
  for (int o = 32; o; o >>= 1) sm += __shfl_xor(sm, o);
  __syncthreads();
  if ((tid & 63) == 0) red[tid >> 6] = sm;
  __syncthreads();
  sm = red[0] + red[1] + red[2] + red[3];
  float inv = 1.0f / sm;
  u16x4 o4;
  o4[0] = f2bf(e[0] * inv); o4[1] = f2bf(e[1] * inv);
  o4[2] = f2bf(e[2] * inv); o4[3] = f2bf(e[3] * inv);
  *(u16x4*)(p + (long)row * SEQ + tid * 4) = o4;
}

// ---------------- LayerNorm over D=1024; optional f32 and bf16 outputs ----------------
__global__ __launch_bounds__(256) void ln_kernel(const float* __restrict__ in,
                                                 const float* __restrict__ g,
                                                 const float* __restrict__ be,
                                                 float* __restrict__ outf,
                                                 u16* __restrict__ outh) {
  int row = blockIdx.x, tid = threadIdx.x;
  f32x4 v = *(const f32x4*)(in + (long)row * DM + tid * 4);
  float s = v[0] + v[1] + v[2] + v[3];
  float q = v[0] * v[0] + v[1] * v[1] + v[2] * v[2] + v[3] * v[3];
  for (int o = 32; o; o >>= 1) { s += __shfl_xor(s, o); q += __shfl_xor(q, o); }
  __shared__ float rs_[4], rq_[4];
  if ((tid & 63) == 0) { rs_[tid >> 6] = s; rq_[tid >> 6] = q; }
  __syncthreads();
  s = rs_[0] + rs_[1] + rs_[2] + rs_[3];
  q = rq_[0] + rq_[1] + rq_[2] + rq_[3];
  float mean = s * (1.0f / DM);
  float var = q * (1.0f / DM) - mean * mean;
  float rstd = rsqrtf(var + 1e-5f);
  f32x4 gg = *(const f32x4*)(g + tid * 4);
  f32x4 bb = *(const f32x4*)(be + tid * 4);
  f32x4 y;
  y[0] = (v[0] - mean) * rstd * gg[0] + bb[0];
  y[1] = (v[1] - mean) * rstd * gg[1] + bb[1];
  y[2] = (v[2] - mean) * rstd * gg[2] + bb[2];
  y[3] = (v[3] - mean) * rstd * gg[3] + bb[3];
  if (outf) *(f32x4*)(outf + (long)row * DM + tid * 4) = y;
  if (outh) {
    u16x4 h;
    h[0] = f2bf(y[0]); h[1] = f2bf(y[1]); h[2] = f2bf(y[2]); h[3] = f2bf(y[3]);
    *(u16x4*)(outh + (long)row * DM + tid * 4) = h;
  }
}

#define GLD(gp, lp)                                              \
  __builtin_amdgcn_global_load_lds(                              \
      (__attribute__((address_space(1))) void*)(gp),             \
      (__attribute__((address_space(3))) void*)(lp), 16, 0, 0)

// ---------------- generic bf16 GEMM (m97 structure): C = A (MxK) * B^T ----------------
#define BM 128
#define BN 128
#define BK 32

__global__ __launch_bounds__(256) void gemm_bt(
    const u16* __restrict__ A, const u16* __restrict__ B,
    float* __restrict__ Cf, u16* __restrict__ Ch,
    const float* __restrict__ bias, const float* __restrict__ resid,
    int K, int lda, int ldb, int ldc,
    long batA, long batB, long batC, int relu) {
  __shared__ u16 As[BM * BK];
  __shared__ u16 Bs[BN * BK];
  const int tid = threadIdx.x;
  const int bz = blockIdx.z;
  A += (long)bz * batA;
  B += (long)bz * batB;
  const long cbase = (long)bz * batC;
  const int row0 = blockIdx.y * BM;
  const int col0 = blockIdx.x * BN;
  const int l = tid & 63;
  const int w = tid >> 6;
  const int wr = (w >> 1) * 64, wc = (w & 1) * 64;

  f32x4 acc[4][4] = {};

  const u16* gA = A + (long)(row0 + (tid >> 2)) * lda + (tid & 3) * 8;
  const u16* gB = B + (long)(col0 + (tid >> 2)) * ldb + (tid & 3) * 8;
  const long a64 = (long)64 * lda, b64 = (long)64 * ldb;
  u16* lA = As + tid * 8;
  u16* lB = Bs + tid * 8;

  const int fr = l & 15;
  const int fk = (l >> 4) * 8;
  const u16* rA = As + (wr + fr) * BK + fk;
  const u16* rB = Bs + (wc + fr) * BK + fk;

  for (int k0 = 0; k0 < K; k0 += BK) {
    GLD(gA + k0, lA);
    GLD(gA + a64 + k0, lA + 2048);
    GLD(gB + k0, lB);
    GLD(gB + b64 + k0, lB + 2048);
    __syncthreads();
    bf16x8 af[4], bf[4];
#pragma unroll
    for (int m = 0; m < 4; ++m) af[m] = *(const bf16x8*)(rA + m * 16 * BK);
#pragma unroll
    for (int n = 0; n < 4; ++n) bf[n] = *(const bf16x8*)(rB + n * 16 * BK);
#pragma unroll
    for (int m = 0; m < 4; ++m)
#pragma unroll
      for (int n = 0; n < 4; ++n)
        acc[m][n] = __builtin_amdgcn_mfma_f32_16x16x32_bf16(af[m], bf[n], acc[m][n], 0, 0, 0);
    __syncthreads();
  }

  const int er = row0 + wr + ((l >> 4) << 2);
  const int ec = col0 + wc + (l & 15);
#pragma unroll
  for (int m = 0; m < 4; ++m) {
#pragma unroll
    for (int n = 0; n < 4; ++n) {
      f32x4 v = acc[m][n];
      const int c = ec + n * 16;
      float bv = bias ? bias[c] : 0.0f;
#pragma unroll
      for (int i = 0; i < 4; ++i) {
        const int r = er + m * 16 + i;
        float x = v[i] + bv;
        if (resid) x += resid[(long)r * ldc + c];
        if (relu) x = fmaxf(x, 0.0f);
        if (Cf) Cf[cbase + (long)r * ldc + c] = x;
        if (Ch) Ch[cbase + (long)r * ldc + c] = f2bf(x);
      }
    }
  }
}

// ---------------- 256x256 8-phase bf16 GEMM (T1+T2+T3+T4+T5): C = A * B^T ----------------
// 512 threads, 8 waves (2M x 4N), BK=64, 2 K-tiles/iter, 1 half-tile staged/phase,
// vmcnt(4) at phases 4/8 only, XOR-swizzled LDS via inverse-swizzled global source.
#define GBK 64

#define DSB() __builtin_amdgcn_sched_barrier(0)
#define SBAR() __builtin_amdgcn_s_barrier()

template <int N0, int N1>
__device__ __forceinline__ void mfma16(f32x4 (&acc)[8][4], const bf16x8 (&af)[8],
                                       bf16x8 b0, bf16x8 b1) {
#pragma unroll
  for (int m = 0; m < 8; ++m) {
    acc[m][N0] = __builtin_amdgcn_mfma_f32_16x16x32_bf16(af[m], b0, acc[m][N0], 0, 0, 0);
    acc[m][N1] = __builtin_amdgcn_mfma_f32_16x16x32_bf16(af[m], b1, acc[m][N1], 0, 0, 0);
  }
}

__global__ __launch_bounds__(512, 2) void gemm256_bt(
    const u16* __restrict__ A, const u16* __restrict__ B,
    float* __restrict__ Cf, u16* __restrict__ Ch,
    const float* __restrict__ bias,
    int K, int lda, int ldb, int ldc, int Mtiles, int relu) {
  __shared__ __align__(16) u16 As[2][256 * GBK];  // 2 x 32KB
  __shared__ __align__(16) u16 Bs[2][256 * GBK];  // 2 x 32KB
  const int tid = threadIdx.x;

  // T1: bijective XCD chunk swizzle (grid % 8 == 0 guaranteed by launch), M-fastest.
  const int nwg = gridDim.x;
  const int blk = blockIdx.x;
  const int cpx = nwg >> 3;
  const int wg = (blk & 7) * cpx + (blk >> 3);
  const int row0 = (wg % Mtiles) * 256;
  const int col0 = (wg / Mtiles) * 256;

  const int l = tid & 63;
  const int w = tid >> 6;  // 0..7
  const int wr = w >> 2;   // 0..1 (M)
  const int wc = w & 3;    // 0..3 (N)

  // staging: chunk c = tid (rows 0..63) and tid+512 (rows 64..127) of a 128-row half-tile.
  const int srow = tid >> 3;                        // 0..63
  const int scol = ((tid & 7) ^ (srow & 7)) * 8;    // inverse-swizzled global col (elements)
  const u16* gA = A + (size_t)(row0 + srow) * lda + scol;
  const u16* gB = B + (size_t)(col0 + srow) * ldb + scol;
  const size_t a64 = (size_t)64 * lda, b64 = (size_t)64 * ldb;

#define STAGE_A(buf, h, kofs)                                       \
  do {                                                              \
    const u16* _g = gA + (size_t)(h) * 128 * lda + (kofs);          \
    u16* _l = &As[buf][(h) * 8192] + tid * 8;                       \
    GLD(_g, _l);                                                    \
    GLD(_g + a64, _l + 4096);                                       \
  } while (0)
#define STAGE_B(buf, h, kofs)                                       \
  do {                                                              \
    const u16* _g = gB + (size_t)(h) * 128 * ldb + (kofs);          \
    u16* _l = &Bs[buf][(h) * 8192] + tid * 8;                       \
    GLD(_g, _l);                                                    \
    GLD(_g + b64, _l + 4096);                                       \
  } while (0)

  // fragment-read constants (swizzled): phys u16 off = row*64 + ((kk*64B + fkb) ^ frsw)/2
  // K-subtile kk spans 64 BYTES (32 bf16) per row; lane group l>>4 reads bytes (l>>4)*16.
  const int fr = l & 15;
  const int fkb = (l >> 4) << 4;          // byte col within subtile
  const int frsw = (fr & 7) << 4;
  const int cp0 = ((0 + fkb) ^ frsw) >> 1;
  const int cp1 = ((64 + fkb) ^ frsw) >> 1;   // FIXED: odd subtile starts at byte 64
  const int abase = (wr * 128 + fr) * 64;
  const int bbase = (wc * 64 + fr) * 64;

#define RA(buf, m, cp) (*(const bf16x8*)(&As[buf][abase + (m) * 1024 + (cp)]))
#define RB(buf, n, cp) (*(const bf16x8*)(&Bs[buf][bbase + (n) * 1024 + (cp)]))

  f32x4 acc[8][4] = {};
  bf16x8 a0[8], a1[8], bb0, bb1;

  const int nkt = K >> 6;       // K-tiles (must be even, >= 2)
  const int nit = nkt >> 1;

  // prologue: tile0 -> buf0 (A0,A1,B0,B1); tile1 -> buf1 (A0,A1)
  STAGE_A(0, 0, 0); STAGE_A(0, 1, 0);
  STAGE_B(0, 0, 0); STAGE_B(0, 1, 0);
  STAGE_A(1, 0, 64); STAGE_A(1, 1, 64);
  asm volatile("s_waitcnt vmcnt(4)"); DSB();
  SBAR();

  for (int i = 0; i < nit; ++i) {
    const int ku = (2 * i + 1) << 6;
    const int t2 = (2 * i + 2 < nkt) ? (2 * i + 2) : (nkt - 1);
    const int u2 = (2 * i + 3 < nkt) ? (2 * i + 3) : (nkt - 1);
    const int kt2 = t2 << 6, ku2 = u2 << 6;

    // ---- phase 1: tile t (buf0), quad(kk0, n01); stage u.B0 ----
#pragma unroll
    for (int m = 0; m < 8; ++m) a0[m] = RA(0, m, cp0);
    bb0 = RB(0, 0, cp0); bb1 = RB(0, 1, cp0);
#pragma unroll
    for (int m = 0; m < 8; ++m) a1[m] = RA(0, m, cp1);
    STAGE_B(1, 0, ku);
    SBAR();
    asm volatile("s_waitcnt lgkmcnt(8)"); DSB();
    __builtin_amdgcn_s_setprio(1);
    mfma16<0, 1>(acc, a0, bb0, bb1);
    __builtin_amdgcn_s_setprio(0);
    SBAR();
    // ---- phase 2: quad(kk0, n23); stage u.B1 ----
    bb0 = RB(0, 2, cp0); bb1 = RB(0, 3, cp0);
    STAGE_B(1, 1, ku);
    SBAR();
    asm volatile("s_waitcnt lgkmcnt(0)"); DSB();
    __builtin_amdgcn_s_setprio(1);
    mfma16<2, 3>(acc, a0, bb0, bb1);
    __builtin_amdgcn_s_setprio(0);
    SBAR();
    // ---- phase 3: quad(kk1, n01); stage (t+2).A0 ----
    bb0 = RB(0, 0, cp1); bb1 = RB(0, 1, cp1);
    STAGE_A(0, 0, kt2);
    SBAR();
    asm volatile("s_waitcnt lgkmcnt(0)"); DSB();
    __builtin_amdgcn_s_setprio(1);
    mfma16<0, 1>(acc, a1, bb0, bb1);
    __builtin_amdgcn_s_setprio(0);
    SBAR();
    // ---- phase 4: quad(kk1, n23); stage (t+2).A1; vmcnt(4) ----
    bb0 = RB(0, 2, cp1); bb1 = RB(0, 3, cp1);
    STAGE_A(0, 1, kt2);
    asm volatile("s_waitcnt vmcnt(4)"); DSB();
    SBAR();
    asm volatile("s_waitcnt lgkmcnt(0)"); DSB();
    __builtin_amdgcn_s_setprio(1);
    mfma16<2, 3>(acc, a1, bb0, bb1);
    __builtin_amdgcn_s_setprio(0);
    SBAR();
    // ---- phase 5: tile u (buf1), quad(kk0, n01); stage (t+2).B0 ----
#pragma unroll
    for (int m = 0; m < 8; ++m) a0[m] = RA(1, m, cp0);
    bb0 = RB(1, 0, cp0); bb1 = RB(1, 1, cp0);
#pragma unroll
    for (int m = 0; m < 8; ++m) a1[m] = RA(1, m, cp1);
    STAGE_B(0, 0, kt2);
    SBAR();
    asm volatile("s_waitcnt lgkmcnt(8)"); DSB();
    __builtin_amdgcn_s_setprio(1);
    mfma16<0, 1>(acc, a0, bb0, bb1);
    __builtin_amdgcn_s_setprio(0);
    SBAR();
    // ---- phase 6: quad(kk0, n23); stage (t+2).B1 ----
    bb0 = RB(1, 2, cp0); bb1 = RB(1, 3, cp0);
    STAGE_B(0, 1, kt2);
    SBAR();
    asm volatile("s_waitcnt lgkmcnt(0)"); DSB();
    __builtin_amdgcn_s_setprio(1);
    mfma16<2, 3>(acc, a0, bb0, bb1);
    __builtin_amdgcn_s_setprio(0);
    SBAR();
    // ---- phase 7: quad(kk1, n01); stage (u+2).A0 ----
    bb0 = RB(1, 0, cp1); bb1 = RB(1, 1, cp1);
    STAGE_A(1, 0, ku2);
    SBAR();
    asm volatile("s_waitcnt lgkmcnt(0)"); DSB();
    __builtin_amdgcn_s_setprio(1);
    mfma16<0, 1>(acc, a1, bb0, bb1);
    __builtin_amdgcn_s_setprio(0);
    SBAR();
    // ---- phase 8: quad(kk1, n23); stage (u+2).A1; vmcnt(4) ----
    bb0 = RB(1, 2, cp1); bb1 = RB(1, 3, cp1);
    STAGE_A(1, 1, ku2);
    asm volatile("s_waitcnt vmcnt(4)"); DSB();
    SBAR();
    asm volatile("s_waitcnt lgkmcnt(0)"); DSB();
    __builtin_amdgcn_s_setprio(1);
    mfma16<2, 3>(acc, a1, bb0, bb1);
    __builtin_amdgcn_s_setprio(0);
    SBAR();
  }

  // drain in-flight LDS-DMA before workgroup teardown
  asm volatile("s_waitcnt vmcnt(0)"); DSB();

  // epilogue
  const int er = row0 + wr * 128 + ((l >> 4) << 2);
  const int ec = col0 + wc * 64 + (l & 15);
#pragma unroll
  for (int m = 0; m < 8; ++m) {
#pragma unroll
    for (int n = 0; n < 4; ++n) {
      f32x4 v = acc[m][n];
      const int c = ec + n * 16;
      float bv = bias ? bias[c] : 0.0f;
#pragma unroll
      for (int i = 0; i < 4; ++i) {
        const int r = er + m * 16 + i;
        float x = v[i] + bv;
        if (relu) x = fmaxf(x, 0.0f);
        if (Cf) Cf[(size_t)r * ldc + c] = x;
        if (Ch) Ch[(size_t)r * ldc + c] = f2bf(x);
      }
    }
  }
#undef STAGE_A
#undef STAGE_B
#undef RA
#undef RB
}

extern "C" void kernel_launch(void* const* d_in, const int* in_sizes, int n_in,
                              void* d_out, int out_size, void* d_ws, size_t ws_size,
                              hipStream_t stream) {
  const int* ids = (const int*)d_in[0];
  const float* tab = (const float*)d_in[1];
  const float* WQ = (const float*)d_in[2];
  const float* WK = (const float*)d_in[3];
  const float* WV = (const float*)d_in[4];
  const float* Wo = (const float*)d_in[5];
  const float* bo = (const float*)d_in[6];
  const float* W1 = (const float*)d_in[7];
  const float* b1 = (const float*)d_in[8];
  const float* W2 = (const float*)d_in[9];
  const float* b2 = (const float*)d_in[10];
  const float* g1 = (const float*)d_in[11];
  const float* be1 = (const float*)d_in[12];
  const float* g2 = (const float*)d_in[13];
  const float* be2 = (const float*)d_in[14];
  const float* Wd = (const float*)d_in[15];
  const float* bd = (const float*)d_in[16];
  float* logits = (float*)d_out;

  if (ws_size < 280000000ull) return;  // need ~276 MB scratch

  char* p = (char*)d_ws;
  auto alloc = [&](size_t bytes) {
    char* r = p;
    p += (bytes + 255) & ~(size_t)255;
    return r;
  };
  float* embf = (float*)alloc((size_t)NT * DM * 4);
  u16* embh = (u16*)alloc((size_t)NT * DM * 2);
  u16* WQh = (u16*)alloc((size_t)DM * DM * 2);
  u16* WKh = (u16*)alloc((size_t)DM * DM * 2);
  u16* WVh = (u16*)alloc((size_t)DM * DM * 2);
  u16* Woh = (u16*)alloc((size_t)DM * DM * 2);
  u16* W1h = (u16*)alloc((size_t)HD * DM * 2);
  u16* W2h = (u16*)alloc((size_t)DM * HD * 2);
  u16* Wdh = (u16*)alloc((size_t)NV * DM * 2);
  u16* Qh = (u16*)alloc((size_t)NT * DM * 2);
  u16* Kh = (u16*)alloc((size_t)NT * DM * 2);
  u16* VTh = (u16*)alloc((size_t)NBATCH * DM * SEQ * 2);
  float* scoresf = (float*)alloc((size_t)NBATCH * SEQ * SEQ * 4);
  u16* Ph = (u16*)alloc((size_t)NBATCH * SEQ * SEQ * 2);
  u16* zh = (u16*)alloc((size_t)NT * DM * 2);
  float* r1f = (float*)alloc((size_t)NT * DM * 4);
  float* xf = (float*)alloc((size_t)NT * DM * 4);
  u16* xh = (u16*)alloc((size_t)NT * DM * 2);
  u16* hh = (u16*)alloc((size_t)NT * HD * 2);
  float* r2f = (float*)alloc((size_t)NT * DM * 4);
  u16* outh = (u16*)alloc((size_t)NT * DM * 2);

  // --- weight casts to bf16 ---
  cast_bf16_kernel<<<dim3(DM * DM / 8 / 256), 256, 0, stream>>>(WQ, WQh, DM * DM / 8);
  cast_bf16_kernel<<<dim3(DM * DM / 8 / 256), 256, 0, stream>>>(WK, WKh, DM * DM / 8);
  cast_bf16_kernel<<<dim3(DM * DM / 8 / 256), 256, 0, stream>>>(WV, WVh, DM * DM / 8);
  cast_bf16_kernel<<<dim3(DM * DM / 8 / 256), 256, 0, stream>>>(Wo, Woh, DM * DM / 8);
  cast_bf16_kernel<<<dim3(HD * DM / 8 / 256), 256, 0, stream>>>(W1, W1h, HD * DM / 8);
  cast_bf16_kernel<<<dim3(DM * HD / 8 / 256), 256, 0, stream>>>(W2, W2h, DM * HD / 8);
  cast_bf16_kernel<<<dim3(NV * DM / 8 / 256), 256, 0, stream>>>(Wd, Wdh, NV * DM / 8);

  // --- embedding ---
  embed_kernel<<<NT, 256, 0, stream>>>(ids, tab, embf, embh);

  // --- Q, K projections (token layout [NT, DM]) ---
  gemm_bt<<<dim3(DM / BN, NT / BM, 1), 256, 0, stream>>>(
      embh, WQh, nullptr, Qh, nullptr, nullptr, DM, DM, DM, DM, 0, 0, 0, 0);
  gemm_bt<<<dim3(DM / BN, NT / BM, 1), 256, 0, stream>>>(
      embh, WKh, nullptr, Kh, nullptr, nullptr, DM, DM, DM, DM, 0, 0, 0, 0);

  // --- V^T per batch: VT[b][e][s] = sum_d WV[e,d] * emb[s,b,d] ---
  gemm_bt<<<dim3(SEQ / BN, DM / BM, NBATCH), 256, 0, stream>>>(
      WVh, embh, nullptr, VTh, nullptr, nullptr, DM, DM, NBATCH * DM, SEQ,
      0, DM, (long)DM * SEQ, 0);

  // --- scores[b][q][k] = Q_b . K_b (scale folded into softmax) ---
  gemm_bt<<<dim3(SEQ / BN, SEQ / BM, NBATCH), 256, 0, stream>>>(
      Qh, Kh, scoresf, nullptr, nullptr, nullptr, DM, NBATCH * DM, NBATCH * DM, SEQ,
      DM, DM, (long)SEQ * SEQ, 0);

  softmax_kernel<<<NBATCH * SEQ, 256, 0, stream>>>(scoresf, Ph);

  // --- Z[b][q][d] = sum_k P[b,q,k] * VT[b,d,k], written to token layout zh ---
  gemm_bt<<<dim3(DM / BN, SEQ / BM, NBATCH), 256, 0, stream>>>(
      Ph, VTh, nullptr, zh, nullptr, nullptr, SEQ, SEQ, SEQ, NBATCH * DM,
      (long)SEQ * SEQ, (long)DM * SEQ, DM, 0);

  // --- r1 = z @ Wo^T + bo + emb ---
  gemm_bt<<<dim3(DM / BN, NT / BM, 1), 256, 0, stream>>>(
      zh, Woh, r1f, nullptr, bo, embf, DM, DM, DM, DM, 0, 0, 0, 0);

  ln_kernel<<<NT, 256, 0, stream>>>(r1f, g1, be1, xf, xh);

  // --- FFN1: 256x256 8-phase kernel (grid 16x16 = 256 blocks) ---
  gemm256_bt<<<dim3((NT / 256) * (HD / 256)), 512, 0, stream>>>(
      xh, W1h, nullptr, hh, b1, DM, DM, DM, HD, NT / 256, 1);
  // --- FFN2 (N=1024 -> only 64 tiles at 256^2; keep m97) ---
  gemm_bt<<<dim3(DM / BN, NT / BM, 1), 256, 0, stream>>>(
      hh, W2h, r2f, nullptr, b2, xf, HD, HD, HD, DM, 0, 0, 0, 0);

  ln_kernel<<<NT, 256, 0, stream>>>(r2f, g2, be2, nullptr, outh);

  // --- logits: 256x256 8-phase kernel (grid 16x125 = 2000 blocks) ---
  gemm256_bt<<<dim3((NT / 256) * (NV / 256)), 512, 0, stream>>>(
      outh, Wdh, logits, nullptr, bd, DM, DM, DM, NV, NT / 256, 0);
}

// Round 4
// 901.179 us; speedup vs baseline: 1.0632x; 1.0307x over previous
//
#include <hip/hip_runtime.h>

typedef float f32x4 __attribute__((ext_vector_type(4)));
typedef __bf16 bf16x8 __attribute__((ext_vector_type(8)));
typedef unsigned short u16;
typedef unsigned short u16x4 __attribute__((ext_vector_type(4)));
typedef unsigned short u16x8 __attribute__((ext_vector_type(8)));
typedef unsigned int u32;

#define SEQ 1024
#define NBATCH 4
#define DM 1024
#define HD 4096
#define NV 32000
#define NT (SEQ * NBATCH)

__device__ __forceinline__ u16 f2bf(float f) {
  u32 u = __builtin_bit_cast(u32, f);
  return (u16)((u + 0x7FFFu + ((u >> 16) & 1u)) >> 16);  // RTNE
}

// ---------------- f32 -> bf16 cast, 8 elems/thread ----------------
__global__ __launch_bounds__(256) void cast_bf16_kernel(const float* __restrict__ in,
                                                        u16* __restrict__ out, int n8) {
  int i = blockIdx.x * 256 + threadIdx.x;
  if (i >= n8) return;
  const f32x4* p = (const f32x4*)(in + (long)i * 8);
  f32x4 a = p[0], b = p[1];
  u16x8 o;
  o[0] = f2bf(a[0]); o[1] = f2bf(a[1]); o[2] = f2bf(a[2]); o[3] = f2bf(a[3]);
  o[4] = f2bf(b[0]); o[5] = f2bf(b[1]); o[6] = f2bf(b[2]); o[7] = f2bf(b[3]);
  *(u16x8*)(out + (long)i * 8) = o;
}

// ---------------- embedding gather: f32 + bf16 copies ----------------
__global__ __launch_bounds__(256) void embed_kernel(const int* __restrict__ ids,
                                                    const float* __restrict__ tab,
                                                    float* __restrict__ ef,
                                                    u16* __restrict__ eh) {
  int t = blockIdx.x, tid = threadIdx.x;
  long id = ids[t];
  f32x4 v = *(const f32x4*)(tab + id * DM + tid * 4);
  *(f32x4*)(ef + (long)t * DM + tid * 4) = v;
  u16x4 h;
  h[0] = f2bf(v[0]); h[1] = f2bf(v[1]); h[2] = f2bf(v[2]); h[3] = f2bf(v[3]);
  *(u16x4*)(eh + (long)t * DM + tid * 4) = h;
}

// ---------------- row softmax (1024 cols), scale 1/32, bf16 out ----------------
__global__ __launch_bounds__(256) void softmax_kernel(const float* __restrict__ s,
                                                      u16* __restrict__ p) {
  int row = blockIdx.x, tid = threadIdx.x;
  const float* rp = s + (long)row * SEQ;
  f32x4 v = *(const f32x4*)(rp + tid * 4);
  float mx = fmaxf(fmaxf(v[0], v[1]), fmaxf(v[2], v[3]));
  for (int o = 32; o; o >>= 1) mx = fmaxf(mx, __shfl_xor(mx, o));
  __shared__ float red[4];
  if ((tid & 63) == 0) red[tid >> 6] = mx;
  __syncthreads();
  mx = fmaxf(fmaxf(red[0], red[1]), fmaxf(red[2], red[3]));
  const float sc = 0.03125f;  // 1/sqrt(1024)
  f32x4 e;
  e[0] = expf((v[0] - mx) * sc); e[1] = expf((v[1] - mx) * sc);
  e[2] = expf((v[2] - mx) * sc); e[3] = expf((v[3] - mx) * sc);
  float sm = e[0] + e[1] + e[2] + e[3];
  for (int o = 32; o; o >>= 1) sm += __shfl_xor(sm, o);
  __syncthreads();
  if ((tid & 63) == 0) red[tid >> 6] = sm;
  __syncthreads();
  sm = red[0] + red[1] + red[2] + red[3];
  float inv = 1.0f / sm;
  u16x4 o4;
  o4[0] = f2bf(e[0] * inv); o4[1] = f2bf(e[1] * inv);
  o4[2] = f2bf(e[2] * inv); o4[3] = f2bf(e[3] * inv);
  *(u16x4*)(p + (long)row * SEQ + tid * 4) = o4;
}

// ---------------- LayerNorm over D=1024; optional f32 and bf16 outputs ----------------
__global__ __launch_bounds__(256) void ln_kernel(const float* __restrict__ in,
                                                 const float* __restrict__ g,
                                                 const float* __restrict__ be,
                                                 float* __restrict__ outf,
                                                 u16* __restrict__ outh) {
  int row = blockIdx.x, tid = threadIdx.x;
  f32x4 v = *(const f32x4*)(in + (long)row * DM + tid * 4);
  float s = v[0] + v[1] + v[2] + v[3];
  float q = v[0] * v[0] + v[1] * v[1] + v[2] * v[2] + v[3] * v[3];
  for (int o = 32; o; o >>= 1) { s += __shfl_xor(s, o); q += __shfl_xor(q, o); }
  __shared__ float rs_[4], rq_[4];
  if ((tid & 63) == 0) { rs_[tid >> 6] = s; rq_[tid >> 6] = q; }
  __syncthreads();
  s = rs_[0] + rs_[1] + rs_[2] + rs_[3];
  q = rq_[0] + rq_[1] + rq_[2] + rq_[3];
  float mean = s * (1.0f / DM);
  float var = q * (1.0f / DM) - mean * mean;
  float rstd = rsqrtf(var + 1e-5f);
  f32x4 gg = *(const f32x4*)(g + tid * 4);
  f32x4 bb = *(const f32x4*)(be + tid * 4);
  f32x4 y;
  y[0] = (v[0] - mean) * rstd * gg[0] + bb[0];
  y[1] = (v[1] - mean) * rstd * gg[1] + bb[1];
  y[2] = (v[2] - mean) * rstd * gg[2] + bb[2];
  y[3] = (v[3] - mean) * rstd * gg[3] + bb[3];
  if (outf) *(f32x4*)(outf + (long)row * DM + tid * 4) = y;
  if (outh) {
    u16x4 h;
    h[0] = f2bf(y[0]); h[1] = f2bf(y[1]); h[2] = f2bf(y[2]); h[3] = f2bf(y[3]);
    *(u16x4*)(outh + (long)row * DM + tid * 4) = h;
  }
}

#define GLD(gp, lp)                                              \
  __builtin_amdgcn_global_load_lds(                              \
      (__attribute__((address_space(1))) void*)(gp),             \
      (__attribute__((address_space(3))) void*)(lp), 16, 0, 0)

// ---------------- generic bf16 GEMM (m97 structure): C = A (MxK) * B^T ----------------
#define BM 128
#define BN 128
#define BK 32

__global__ __launch_bounds__(256) void gemm_bt(
    const u16* __restrict__ A, const u16* __restrict__ B,
    float* __restrict__ Cf, u16* __restrict__ Ch,
    const float* __restrict__ bias, const float* __restrict__ resid,
    int K, int lda, int ldb, int ldc,
    long batA, long batB, long batC, int relu) {
  __shared__ u16 As[BM * BK];
  __shared__ u16 Bs[BN * BK];
  const int tid = threadIdx.x;
  const int bz = blockIdx.z;
  A += (long)bz * batA;
  B += (long)bz * batB;
  const long cbase = (long)bz * batC;
  const int row0 = blockIdx.y * BM;
  const int col0 = blockIdx.x * BN;
  const int l = tid & 63;
  const int w = tid >> 6;
  const int wr = (w >> 1) * 64, wc = (w & 1) * 64;

  f32x4 acc[4][4] = {};

  const u16* gA = A + (long)(row0 + (tid >> 2)) * lda + (tid & 3) * 8;
  const u16* gB = B + (long)(col0 + (tid >> 2)) * ldb + (tid & 3) * 8;
  const long a64 = (long)64 * lda, b64 = (long)64 * ldb;
  u16* lA = As + tid * 8;
  u16* lB = Bs + tid * 8;

  const int fr = l & 15;
  const int fk = (l >> 4) * 8;
  const u16* rA = As + (wr + fr) * BK + fk;
  const u16* rB = Bs + (wc + fr) * BK + fk;

  for (int k0 = 0; k0 < K; k0 += BK) {
    GLD(gA + k0, lA);
    GLD(gA + a64 + k0, lA + 2048);
    GLD(gB + k0, lB);
    GLD(gB + b64 + k0, lB + 2048);
    __syncthreads();
    bf16x8 af[4], bf[4];
#pragma unroll
    for (int m = 0; m < 4; ++m) af[m] = *(const bf16x8*)(rA + m * 16 * BK);
#pragma unroll
    for (int n = 0; n < 4; ++n) bf[n] = *(const bf16x8*)(rB + n * 16 * BK);
#pragma unroll
    for (int m = 0; m < 4; ++m)
#pragma unroll
      for (int n = 0; n < 4; ++n)
        acc[m][n] = __builtin_amdgcn_mfma_f32_16x16x32_bf16(af[m], bf[n], acc[m][n], 0, 0, 0);
    __syncthreads();
  }

  const int er = row0 + wr + ((l >> 4) << 2);
  const int ec = col0 + wc + (l & 15);
#pragma unroll
  for (int m = 0; m < 4; ++m) {
#pragma unroll
    for (int n = 0; n < 4; ++n) {
      f32x4 v = acc[m][n];
      const int c = ec + n * 16;
      float bv = bias ? bias[c] : 0.0f;
#pragma unroll
      for (int i = 0; i < 4; ++i) {
        const int r = er + m * 16 + i;
        float x = v[i] + bv;
        if (resid) x += resid[(long)r * ldc + c];
        if (relu) x = fmaxf(x, 0.0f);
        if (Cf) Cf[cbase + (long)r * ldc + c] = x;
        if (Ch) Ch[cbase + (long)r * ldc + c] = f2bf(x);
      }
    }
  }
}

// ---------------- 256x256 8-phase bf16 GEMM v2 (deep pipeline): C = A * B^T ----------------
// 512 thr / 8 waves (2M x 4N). A: M-split halves, 128B rows, 3-bit XOR swizzle (0-conflict).
// B: K-split halves, 64B rows, 2-bit XOR swizzle. Rota gives every stage >=3 phases of
// flight; counted vmcnt(6) at phases 2/4/6/8 (mid-phase, before barrier) covers next reads.
#define DSB() __builtin_amdgcn_sched_barrier(0)
#define SBAR() __builtin_amdgcn_s_barrier()

template <int N0, int N1>
__device__ __forceinline__ void mfma16(f32x4 (&acc)[8][4], const bf16x8 (&af)[8],
                                       bf16x8 b0, bf16x8 b1) {
#pragma unroll
  for (int m = 0; m < 8; ++m) {
    acc[m][N0] = __builtin_amdgcn_mfma_f32_16x16x32_bf16(af[m], b0, acc[m][N0], 0, 0, 0);
    acc[m][N1] = __builtin_amdgcn_mfma_f32_16x16x32_bf16(af[m], b1, acc[m][N1], 0, 0, 0);
  }
}

__global__ __launch_bounds__(512, 2) void gemm256_bt(
    const u16* __restrict__ A, const u16* __restrict__ B,
    float* __restrict__ Cf, u16* __restrict__ Ch,
    const float* __restrict__ bias,
    int K, int lda, int ldb, int ldc, int Mtiles, int relu) {
  __shared__ __align__(16) u16 As[2][2][128 * 64];  // [buf][Mhalf][row(128B-stride)] 64KB
  __shared__ __align__(16) u16 Bs[2][2][256 * 32];  // [buf][Khalf][row(64B-stride)]  64KB
  const int tid = threadIdx.x;

  // T1: bijective XCD chunk swizzle (grid % 8 == 0), M-fastest within chunk.
  const int nwg = gridDim.x;
  const int blk = blockIdx.x;
  const int cpx = nwg >> 3;
  const int wg = (blk & 7) * cpx + (blk >> 3);
  const int row0 = (wg % Mtiles) * 256;
  const int col0 = (wg / Mtiles) * 256;

  const int l = tid & 63;
  const int w = tid >> 6;  // 0..7
  const int wr = w >> 2;   // 0..1 (M)
  const int wc = w & 3;    // 0..3 (N)

  // A staging: half = 128 rows x 64k (16KB). chunk c: row=c>>3, slot=c&7 (16B),
  // fetch global col pre-swizzled: gcol16 = slot ^ (row&7).
  const int sArow = tid >> 3;                       // 0..63
  const int sAcol = ((tid & 7) ^ (sArow & 7)) * 8;  // elements
  // B staging: half = 256 rows x 32k (16KB). chunk c: row=c>>2, slot=c&3,
  // gcol16 = slot ^ (row&3).
  const int sBrow = tid >> 2;                       // 0..127
  const int sBcol = ((tid & 3) ^ (sBrow & 3)) * 8;

  const u16* gA = A + (size_t)(row0 + sArow) * lda + sAcol;
  const u16* gB = B + (size_t)(col0 + sBrow) * ldb + sBcol;
  const size_t a64 = (size_t)64 * lda;
  const size_t b128 = (size_t)128 * ldb;

#define STAGE_A(buf, h, kt)                                          \
  do {                                                               \
    const u16* _g = gA + (size_t)(h) * 128 * lda + (size_t)(kt) * 64;\
    u16* _l = &As[buf][h][0] + tid * 8;                              \
    GLD(_g, _l);                                                     \
    GLD(_g + a64, _l + 4096);                                        \
  } while (0)
#define STAGE_B(buf, kk, kt)                                         \
  do {                                                               \
    const u16* _g = gB + (size_t)(kt) * 64 + (kk) * 32;              \
    u16* _l = &Bs[buf][kk][0] + tid * 8;                             \
    GLD(_g, _l);                                                     \
    GLD(_g + b128, _l + 4096);                                       \
  } while (0)

  // fragment read offsets (u16), swizzle-aware
  const int fr = l & 15;
  const int g8 = (l >> 4) * 8;                 // 16B slot * 8 u16
  const int acp0 = g8 ^ ((fr & 7) * 8);        // A kk0
  const int acp1 = (32 + g8) ^ ((fr & 7) * 8); // A kk1 (slot 4..7)
  const int bcp = g8 ^ ((fr & 3) * 8);         // B within 64B row

#define RA(buf, m, cp) (*(const bf16x8*)(&As[buf][wr][((m) * 16 + fr) * 64 + (cp)]))
#define RB(buf, n, kk) (*(const bf16x8*)(&Bs[buf][kk][(wc * 64 + (n) * 16 + fr) * 32 + bcp]))

  f32x4 acc[8][4] = {};
  bf16x8 a0[8], a1[8], bb0, bb1;

  const int nkt = K >> 6;  // >= 2, even
  const int nit = nkt >> 1;

  // prologue: t0 fully (4 halves), then t1.Bk0, t1.Ah0 (rota supplies t1.Ah1@p1, t1.Bk1@p2)
  STAGE_A(0, 0, 0); STAGE_A(0, 1, 0);
  STAGE_B(0, 0, 0); STAGE_B(0, 1, 0);
  STAGE_B(1, 0, 1); STAGE_A(1, 0, 1);
  asm volatile("s_waitcnt vmcnt(4)"); DSB();
  SBAR();

  for (int i = 0; i < nit; ++i) {
    const int u = 2 * i + 1;
    const int v = (2 * i + 2 < nkt) ? 2 * i + 2 : nkt - 1;
    const int w2 = (2 * i + 3 < nkt) ? 2 * i + 3 : nkt - 1;

    // ---- p1: t(kk0,n01); stage u.Ah1 ----
#pragma unroll
    for (int m = 0; m < 8; ++m) a0[m] = RA(0, m, acp0);
    bb0 = RB(0, 0, 0); bb1 = RB(0, 1, 0);
    STAGE_A(1, 1, u);
    SBAR();
    asm volatile("s_waitcnt lgkmcnt(0)"); DSB();
    __builtin_amdgcn_s_setprio(1);
    mfma16<0, 1>(acc, a0, bb0, bb1);
    __builtin_amdgcn_s_setprio(0);
    SBAR();
    // ---- p2: t(kk0,n23); stage u.Bk1; vmcnt(6) ----
    bb0 = RB(0, 2, 0); bb1 = RB(0, 3, 0);
    STAGE_B(1, 1, u);
    asm volatile("s_waitcnt vmcnt(6)"); DSB();
    SBAR();
    asm volatile("s_waitcnt lgkmcnt(0)"); DSB();
    __builtin_amdgcn_s_setprio(1);
    mfma16<2, 3>(acc, a0, bb0, bb1);
    __builtin_amdgcn_s_setprio(0);
    SBAR();
    // ---- p3: t(kk1,n01); stage v.Bk0 ----
#pragma unroll
    for (int m = 0; m < 8; ++m) a1[m] = RA(0, m, acp1);
    bb0 = RB(0, 0, 1); bb1 = RB(0, 1, 1);
    STAGE_B(0, 0, v);
    SBAR();
    asm volatile("s_waitcnt lgkmcnt(0)"); DSB();
    __builtin_amdgcn_s_setprio(1);
    mfma16<0, 1>(acc, a1, bb0, bb1);
    __builtin_amdgcn_s_setprio(0);
    SBAR();
    // ---- p4: t(kk1,n23); stage v.Ah0; vmcnt(6) ----
    bb0 = RB(0, 2, 1); bb1 = RB(0, 3, 1);
    STAGE_A(0, 0, v);
    asm volatile("s_waitcnt vmcnt(6)"); DSB();
    SBAR();
    asm volatile("s_waitcnt lgkmcnt(0)"); DSB();
    __builtin_amdgcn_s_setprio(1);
    mfma16<2, 3>(acc, a1, bb0, bb1);
    __builtin_amdgcn_s_setprio(0);
    SBAR();
    // ---- p5: u(kk0,n01); stage v.Ah1 ----
#pragma unroll
    for (int m = 0; m < 8; ++m) a0[m] = RA(1, m, acp0);
    bb0 = RB(1, 0, 0); bb1 = RB(1, 1, 0);
    STAGE_A(0, 1, v);
    SBAR();
    asm volatile("s_waitcnt lgkmcnt(0)"); DSB();
    __builtin_amdgcn_s_setprio(1);
    mfma16<0, 1>(acc, a0, bb0, bb1);
    __builtin_amdgcn_s_setprio(0);
    SBAR();
    // ---- p6: u(kk0,n23); stage v.Bk1; vmcnt(6) ----
    bb0 = RB(1, 2, 0); bb1 = RB(1, 3, 0);
    STAGE_B(0, 1, v);
    asm volatile("s_waitcnt vmcnt(6)"); DSB();
    SBAR();
    asm volatile("s_waitcnt lgkmcnt(0)"); DSB();
    __builtin_amdgcn_s_setprio(1);
    mfma16<2, 3>(acc, a0, bb0, bb1);
    __builtin_amdgcn_s_setprio(0);
    SBAR();
    // ---- p7: u(kk1,n01); stage w.Bk0 ----
#pragma unroll
    for (int m = 0; m < 8; ++m) a1[m] = RA(1, m, acp1);
    bb0 = RB(1, 0, 1); bb1 = RB(1, 1, 1);
    STAGE_B(1, 0, w2);
    SBAR();
    asm volatile("s_waitcnt lgkmcnt(0)"); DSB();
    __builtin_amdgcn_s_setprio(1);
    mfma16<0, 1>(acc, a1, bb0, bb1);
    __builtin_amdgcn_s_setprio(0);
    SBAR();
    // ---- p8: u(kk1,n23); stage w.Ah0; vmcnt(6) ----
    bb0 = RB(1, 2, 1); bb1 = RB(1, 3, 1);
    STAGE_A(1, 0, w2);
    asm volatile("s_waitcnt vmcnt(6)"); DSB();
    SBAR();
    asm volatile("s_waitcnt lgkmcnt(0)"); DSB();
    __builtin_amdgcn_s_setprio(1);
    mfma16<2, 3>(acc, a1, bb0, bb1);
    __builtin_amdgcn_s_setprio(0);
    SBAR();
  }

  // drain in-flight LDS-DMA before teardown
  asm volatile("s_waitcnt vmcnt(0)"); DSB();

  // epilogue
  const int er = row0 + wr * 128 + ((l >> 4) << 2);
  const int ec = col0 + wc * 64 + (l & 15);
#pragma unroll
  for (int m = 0; m < 8; ++m) {
#pragma unroll
    for (int n = 0; n < 4; ++n) {
      f32x4 vv = acc[m][n];
      const int c = ec + n * 16;
      float bv = bias ? bias[c] : 0.0f;
#pragma unroll
      for (int i = 0; i < 4; ++i) {
        const int r = er + m * 16 + i;
        float x = vv[i] + bv;
        if (relu) x = fmaxf(x, 0.0f);
        if (Cf) Cf[(size_t)r * ldc + c] = x;
        if (Ch) Ch[(size_t)r * ldc + c] = f2bf(x);
      }
    }
  }
#undef STAGE_A
#undef STAGE_B
#undef RA
#undef RB
}

extern "C" void kernel_launch(void* const* d_in, const int* in_sizes, int n_in,
                              void* d_out, int out_size, void* d_ws, size_t ws_size,
                              hipStream_t stream) {
  const int* ids = (const int*)d_in[0];
  const float* tab = (const float*)d_in[1];
  const float* WQ = (const float*)d_in[2];
  const float* WK = (const float*)d_in[3];
  const float* WV = (const float*)d_in[4];
  const float* Wo = (const float*)d_in[5];
  const float* bo = (const float*)d_in[6];
  const float* W1 = (const float*)d_in[7];
  const float* b1 = (const float*)d_in[8];
  const float* W2 = (const float*)d_in[9];
  const float* b2 = (const float*)d_in[10];
  const float* g1 = (const float*)d_in[11];
  const float* be1 = (const float*)d_in[12];
  const float* g2 = (const float*)d_in[13];
  const float* be2 = (const float*)d_in[14];
  const float* Wd = (const float*)d_in[15];
  const float* bd = (const float*)d_in[16];
  float* logits = (float*)d_out;

  if (ws_size < 280000000ull) return;  // need ~276 MB scratch

  char* p = (char*)d_ws;
  auto alloc = [&](size_t bytes) {
    char* r = p;
    p += (bytes + 255) & ~(size_t)255;
    return r;
  };
  float* embf = (float*)alloc((size_t)NT * DM * 4);
  u16* embh = (u16*)alloc((size_t)NT * DM * 2);
  u16* WQh = (u16*)alloc((size_t)DM * DM * 2);
  u16* WKh = (u16*)alloc((size_t)DM * DM * 2);
  u16* WVh = (u16*)alloc((size_t)DM * DM * 2);
  u16* Woh = (u16*)alloc((size_t)DM * DM * 2);
  u16* W1h = (u16*)alloc((size_t)HD * DM * 2);
  u16* W2h = (u16*)alloc((size_t)DM * HD * 2);
  u16* Wdh = (u16*)alloc((size_t)NV * DM * 2);
  u16* Qh = (u16*)alloc((size_t)NT * DM * 2);
  u16* Kh = (u16*)alloc((size_t)NT * DM * 2);
  u16* VTh = (u16*)alloc((size_t)NBATCH * DM * SEQ * 2);
  float* scoresf = (float*)alloc((size_t)NBATCH * SEQ * SEQ * 4);
  u16* Ph = (u16*)alloc((size_t)NBATCH * SEQ * SEQ * 2);
  u16* zh = (u16*)alloc((size_t)NT * DM * 2);
  float* r1f = (float*)alloc((size_t)NT * DM * 4);
  float* xf = (float*)alloc((size_t)NT * DM * 4);
  u16* xh = (u16*)alloc((size_t)NT * DM * 2);
  u16* hh = (u16*)alloc((size_t)NT * HD * 2);
  float* r2f = (float*)alloc((size_t)NT * DM * 4);
  u16* outh = (u16*)alloc((size_t)NT * DM * 2);

  // --- weight casts to bf16 ---
  cast_bf16_kernel<<<dim3(DM * DM / 8 / 256), 256, 0, stream>>>(WQ, WQh, DM * DM / 8);
  cast_bf16_kernel<<<dim3(DM * DM / 8 / 256), 256, 0, stream>>>(WK, WKh, DM * DM / 8);
  cast_bf16_kernel<<<dim3(DM * DM / 8 / 256), 256, 0, stream>>>(WV, WVh, DM * DM / 8);
  cast_bf16_kernel<<<dim3(DM * DM / 8 / 256), 256, 0, stream>>>(Wo, Woh, DM * DM / 8);
  cast_bf16_kernel<<<dim3(HD * DM / 8 / 256), 256, 0, stream>>>(W1, W1h, HD * DM / 8);
  cast_bf16_kernel<<<dim3(DM * HD / 8 / 256), 256, 0, stream>>>(W2, W2h, DM * HD / 8);
  cast_bf16_kernel<<<dim3(NV * DM / 8 / 256), 256, 0, stream>>>(Wd, Wdh, NV * DM / 8);

  // --- embedding ---
  embed_kernel<<<NT, 256, 0, stream>>>(ids, tab, embf, embh);

  // --- Q, K projections (token layout [NT, DM]) ---
  gemm_bt<<<dim3(DM / BN, NT / BM, 1), 256, 0, stream>>>(
      embh, WQh, nullptr, Qh, nullptr, nullptr, DM, DM, DM, DM, 0, 0, 0, 0);
  gemm_bt<<<dim3(DM / BN, NT / BM, 1), 256, 0, stream>>>(
      embh, WKh, nullptr, Kh, nullptr, nullptr, DM, DM, DM, DM, 0, 0, 0, 0);

  // --- V^T per batch: VT[b][e][s] = sum_d WV[e,d] * emb[s,b,d] ---
  gemm_bt<<<dim3(SEQ / BN, DM / BM, NBATCH), 256, 0, stream>>>(
      WVh, embh, nullptr, VTh, nullptr, nullptr, DM, DM, NBATCH * DM, SEQ,
      0, DM, (long)DM * SEQ, 0);

  // --- scores[b][q][k] = Q_b . K_b (scale folded into softmax) ---
  gemm_bt<<<dim3(SEQ / BN, SEQ / BM, NBATCH), 256, 0, stream>>>(
      Qh, Kh, scoresf, nullptr, nullptr, nullptr, DM, NBATCH * DM, NBATCH * DM, SEQ,
      DM, DM, (long)SEQ * SEQ, 0);

  softmax_kernel<<<NBATCH * SEQ, 256, 0, stream>>>(scoresf, Ph);

  // --- Z[b][q][d] = sum_k P[b,q,k] * VT[b,d,k], written to token layout zh ---
  gemm_bt<<<dim3(DM / BN, SEQ / BM, NBATCH), 256, 0, stream>>>(
      Ph, VTh, nullptr, zh, nullptr, nullptr, SEQ, SEQ, SEQ, NBATCH * DM,
      (long)SEQ * SEQ, (long)DM * SEQ, DM, 0);

  // --- r1 = z @ Wo^T + bo + emb ---
  gemm_bt<<<dim3(DM / BN, NT / BM, 1), 256, 0, stream>>>(
      zh, Woh, r1f, nullptr, bo, embf, DM, DM, DM, DM, 0, 0, 0, 0);

  ln_kernel<<<NT, 256, 0, stream>>>(r1f, g1, be1, xf, xh);

  // --- FFN1: 256x256 8-phase v2 (grid 16x16 = 256 blocks) ---
  gemm256_bt<<<dim3((NT / 256) * (HD / 256)), 512, 0, stream>>>(
      xh, W1h, nullptr, hh, b1, DM, DM, DM, HD, NT / 256, 1);
  // --- FFN2 (keep m97) ---
  gemm_bt<<<dim3(DM / BN, NT / BM, 1), 256, 0, stream>>>(
      hh, W2h, r2f, nullptr, b2, xf, HD, HD, HD, DM, 0, 0, 0, 0);

  ln_kernel<<<NT, 256, 0, stream>>>(r2f, g2, be2, nullptr, outh);

  // --- logits: 256x256 8-phase v2 (grid 16x125 = 2000 blocks) ---
  gemm256_bt<<<dim3((NT / 256) * (NV / 256)), 512, 0, stream>>>(
      outh, Wdh, logits, nullptr, bd, DM, DM, DM, NV, NT / 256, 0);
}

// Round 5
// 877.615 us; speedup vs baseline: 1.0918x; 1.0269x over previous
//
#include <hip/hip_runtime.h>

typedef float f32x4 __attribute__((ext_vector_type(4)));
typedef __bf16 bf16x8 __attribute__((ext_vector_type(8)));
typedef unsigned short u16;
typedef unsigned short u16x4 __attribute__((ext_vector_type(4)));
typedef unsigned short u16x8 __attribute__((ext_vector_type(8)));
typedef unsigned int u32;

#define SEQ 1024
#define NBATCH 4
#define DM 1024
#define HD 4096
#define NV 32000
#define NT (SEQ * NBATCH)

__device__ __forceinline__ u16 f2bf(float f) {
  u32 u = __builtin_bit_cast(u32, f);
  return (u16)((u + 0x7FFFu + ((u >> 16) & 1u)) >> 16);  // RTNE
}

// ---------------- f32 -> bf16 cast, 8 elems/thread ----------------
__global__ __launch_bounds__(256) void cast_bf16_kernel(const float* __restrict__ in,
                                                        u16* __restrict__ out, int n8) {
  int i = blockIdx.x * 256 + threadIdx.x;
  if (i >= n8) return;
  const f32x4* p = (const f32x4*)(in + (long)i * 8);
  f32x4 a = p[0], b = p[1];
  u16x8 o;
  o[0] = f2bf(a[0]); o[1] = f2bf(a[1]); o[2] = f2bf(a[2]); o[3] = f2bf(a[3]);
  o[4] = f2bf(b[0]); o[5] = f2bf(b[1]); o[6] = f2bf(b[2]); o[7] = f2bf(b[3]);
  *(u16x8*)(out + (long)i * 8) = o;
}

// ---------------- embedding gather: f32 + bf16 copies ----------------
__global__ __launch_bounds__(256) void embed_kernel(const int* __restrict__ ids,
                                                    const float* __restrict__ tab,
                                                    float* __restrict__ ef,
                                                    u16* __restrict__ eh) {
  int t = blockIdx.x, tid = threadIdx.x;
  long id = ids[t];
  f32x4 v = *(const f32x4*)(tab + id * DM + tid * 4);
  *(f32x4*)(ef + (long)t * DM + tid * 4) = v;
  u16x4 h;
  h[0] = f2bf(v[0]); h[1] = f2bf(v[1]); h[2] = f2bf(v[2]); h[3] = f2bf(v[3]);
  *(u16x4*)(eh + (long)t * DM + tid * 4) = h;
}

// ---------------- row softmax (1024 cols), scale 1/32, bf16 out ----------------
__global__ __launch_bounds__(256) void softmax_kernel(const float* __restrict__ s,
                                                      u16* __restrict__ p) {
  int row = blockIdx.x, tid = threadIdx.x;
  const float* rp = s + (long)row * SEQ;
  f32x4 v = *(const f32x4*)(rp + tid * 4);
  float mx = fmaxf(fmaxf(v[0], v[1]), fmaxf(v[2], v[3]));
  for (int o = 32; o; o >>= 1) mx = fmaxf(mx, __shfl_xor(mx, o));
  __shared__ float red[4];
  if ((tid & 63) == 0) red[tid >> 6] = mx;
  __syncthreads();
  mx = fmaxf(fmaxf(red[0], red[1]), fmaxf(red[2], red[3]));
  const float sc = 0.03125f;  // 1/sqrt(1024)
  f32x4 e;
  e[0] = expf((v[0] - mx) * sc); e[1] = expf((v[1] - mx) * sc);
  e[2] = expf((v[2] - mx) * sc); e[3] = expf((v[3] - mx) * sc);
  float sm = e[0] + e[1] + e[2] + e[3];
  for (int o = 32; o; o >>= 1) sm += __shfl_xor(sm, o);
  __syncthreads();
  if ((tid & 63) == 0) red[tid >> 6] = sm;
  __syncthreads();
  sm = red[0] + red[1] + red[2] + red[3];
  float inv = 1.0f / sm;
  u16x4 o4;
  o4[0] = f2bf(e[0] * inv); o4[1] = f2bf(e[1] * inv);
  o4[2] = f2bf(e[2] * inv); o4[3] = f2bf(e[3] * inv);
  *(u16x4*)(p + (long)row * SEQ + tid * 4) = o4;
}

// ---------------- LayerNorm over D=1024; optional f32 and bf16 outputs ----------------
__global__ __launch_bounds__(256) void ln_kernel(const float* __restrict__ in,
                                                 const float* __restrict__ g,
                                                 const float* __restrict__ be,
                                                 float* __restrict__ outf,
                                                 u16* __restrict__ outh) {
  int row = blockIdx.x, tid = threadIdx.x;
  f32x4 v = *(const f32x4*)(in + (long)row * DM + tid * 4);
  float s = v[0] + v[1] + v[2] + v[3];
  float q = v[0] * v[0] + v[1] * v[1] + v[2] * v[2] + v[3] * v[3];
  for (int o = 32; o; o >>= 1) { s += __shfl_xor(s, o); q += __shfl_xor(q, o); }
  __shared__ float rs_[4], rq_[4];
  if ((tid & 63) == 0) { rs_[tid >> 6] = s; rq_[tid >> 6] = q; }
  __syncthreads();
  s = rs_[0] + rs_[1] + rs_[2] + rs_[3];
  q = rq_[0] + rq_[1] + rq_[2] + rq_[3];
  float mean = s * (1.0f / DM);
  float var = q * (1.0f / DM) - mean * mean;
  float rstd = rsqrtf(var + 1e-5f);
  f32x4 gg = *(const f32x4*)(g + tid * 4);
  f32x4 bb = *(const f32x4*)(be + tid * 4);
  f32x4 y;
  y[0] = (v[0] - mean) * rstd * gg[0] + bb[0];
  y[1] = (v[1] - mean) * rstd * gg[1] + bb[1];
  y[2] = (v[2] - mean) * rstd * gg[2] + bb[2];
  y[3] = (v[3] - mean) * rstd * gg[3] + bb[3];
  if (outf) *(f32x4*)(outf + (long)row * DM + tid * 4) = y;
  if (outh) {
    u16x4 h;
    h[0] = f2bf(y[0]); h[1] = f2bf(y[1]); h[2] = f2bf(y[2]); h[3] = f2bf(y[3]);
    *(u16x4*)(outh + (long)row * DM + tid * 4) = h;
  }
}

#define GLD(gp, lp)                                              \
  __builtin_amdgcn_global_load_lds(                              \
      (__attribute__((address_space(1))) void*)(gp),             \
      (__attribute__((address_space(3))) void*)(lp), 16, 0, 0)

// ---------------- generic bf16 GEMM (m97 structure): C = A (MxK) * B^T ----------------
#define BM 128
#define BN 128
#define BK 32

__global__ __launch_bounds__(256) void gemm_bt(
    const u16* __restrict__ A, const u16* __restrict__ B,
    float* __restrict__ Cf, u16* __restrict__ Ch,
    const float* __restrict__ bias, const float* __restrict__ resid,
    int K, int lda, int ldb, int ldc,
    long batA, long batB, long batC, int relu) {
  __shared__ u16 As[BM * BK];
  __shared__ u16 Bs[BN * BK];
  const int tid = threadIdx.x;
  const int bz = blockIdx.z;
  A += (long)bz * batA;
  B += (long)bz * batB;
  const long cbase = (long)bz * batC;
  const int row0 = blockIdx.y * BM;
  const int col0 = blockIdx.x * BN;
  const int l = tid & 63;
  const int w = tid >> 6;
  const int wr = (w >> 1) * 64, wc = (w & 1) * 64;

  f32x4 acc[4][4] = {};

  const u16* gA = A + (long)(row0 + (tid >> 2)) * lda + (tid & 3) * 8;
  const u16* gB = B + (long)(col0 + (tid >> 2)) * ldb + (tid & 3) * 8;
  const long a64 = (long)64 * lda, b64 = (long)64 * ldb;
  u16* lA = As + tid * 8;
  u16* lB = Bs + tid * 8;

  const int fr = l & 15;
  const int fk = (l >> 4) * 8;
  const u16* rA = As + (wr + fr) * BK + fk;
  const u16* rB = Bs + (wc + fr) * BK + fk;

  for (int k0 = 0; k0 < K; k0 += BK) {
    GLD(gA + k0, lA);
    GLD(gA + a64 + k0, lA + 2048);
    GLD(gB + k0, lB);
    GLD(gB + b64 + k0, lB + 2048);
    __syncthreads();
    bf16x8 af[4], bf[4];
#pragma unroll
    for (int m = 0; m < 4; ++m) af[m] = *(const bf16x8*)(rA + m * 16 * BK);
#pragma unroll
    for (int n = 0; n < 4; ++n) bf[n] = *(const bf16x8*)(rB + n * 16 * BK);
#pragma unroll
    for (int m = 0; m < 4; ++m)
#pragma unroll
      for (int n = 0; n < 4; ++n)
        acc[m][n] = __builtin_amdgcn_mfma_f32_16x16x32_bf16(af[m], bf[n], acc[m][n], 0, 0, 0);
    __syncthreads();
  }

  const int er = row0 + wr + ((l >> 4) << 2);
  const int ec = col0 + wc + (l & 15);
#pragma unroll
  for (int m = 0; m < 4; ++m) {
#pragma unroll
    for (int n = 0; n < 4; ++n) {
      f32x4 v = acc[m][n];
      const int c = ec + n * 16;
      float bv = bias ? bias[c] : 0.0f;
#pragma unroll
      for (int i = 0; i < 4; ++i) {
        const int r = er + m * 16 + i;
        float x = v[i] + bv;
        if (resid) x += resid[(long)r * ldc + c];
        if (relu) x = fmaxf(x, 0.0f);
        if (Cf) Cf[cbase + (long)r * ldc + c] = x;
        if (Ch) Ch[cbase + (long)r * ldc + c] = f2bf(x);
      }
    }
  }
}

// ---------------- 256x256 8-phase bf16 GEMM v3: C = A * B^T ----------------
// v2 deep-pipeline rota + (a) GROUP_M=4 grouped ordering inside XCD chunks so each
// XCD's A-panels stay L2-resident (fetch was L3-BW-bound), (b) bank-perfect swizzles:
// A (128B rows): slot ^= (row>>1)&7 ; B (64B rows): slot ^= (row>>2)&3.
#define DSB() __builtin_amdgcn_sched_barrier(0)
#define SBAR() __builtin_amdgcn_s_barrier()

template <int N0, int N1>
__device__ __forceinline__ void mfma16(f32x4 (&acc)[8][4], const bf16x8 (&af)[8],
                                       bf16x8 b0, bf16x8 b1) {
#pragma unroll
  for (int m = 0; m < 8; ++m) {
    acc[m][N0] = __builtin_amdgcn_mfma_f32_16x16x32_bf16(af[m], b0, acc[m][N0], 0, 0, 0);
    acc[m][N1] = __builtin_amdgcn_mfma_f32_16x16x32_bf16(af[m], b1, acc[m][N1], 0, 0, 0);
  }
}

__global__ __launch_bounds__(512, 2) void gemm256_bt(
    const u16* __restrict__ A, const u16* __restrict__ B,
    float* __restrict__ Cf, u16* __restrict__ Ch,
    const float* __restrict__ bias,
    int K, int lda, int ldb, int ldc, int Mtiles, int Ntiles, int relu) {
  __shared__ __align__(16) u16 As[2][2][128 * 64];  // [buf][Mhalf][row(128B-stride)] 64KB
  __shared__ __align__(16) u16 Bs[2][2][256 * 32];  // [buf][Khalf][row(64B-stride)]  64KB
  const int tid = threadIdx.x;

  // T1: bijective XCD chunk swizzle (grid % 8 == 0), then GROUP_M=4 grouped order:
  // consecutive wg = 4 M-tiles of one N-column -> each XCD chunk spans only 4 A-panels.
  const int nwg = gridDim.x;
  const int blk = blockIdx.x;
  const int cpx = nwg >> 3;
  const int wg = (blk & 7) * cpx + (blk >> 3);
  const int gsz = 4 * Ntiles;           // Mtiles % 4 == 0 for all our launches
  const int gid = wg / gsz;
  const int rem = wg - gid * gsz;
  const int row0 = (gid * 4 + (rem & 3)) * 256;
  const int col0 = (rem >> 2) * 256;

  const int l = tid & 63;
  const int w = tid >> 6;  // 0..7
  const int wr = w >> 2;   // 0..1 (M)
  const int wc = w & 3;    // 0..3 (N)

  // A staging: half = 128 rows x 64k (16KB). chunk c: row=c>>3, slot=c&7 (16B),
  // global col pre-swizzled: slot ^ ((row>>1)&7)  (bank-perfect for 128B rows).
  const int sArow = tid >> 3;                              // 0..63
  const int sAcol = ((tid & 7) ^ ((sArow >> 1) & 7)) * 8;  // elements
  // B staging: half = 256 rows x 32k (16KB). chunk c: row=c>>2, slot=c&3,
  // global col pre-swizzled: slot ^ ((row>>2)&3)  (bank-perfect for 64B rows).
  const int sBrow = tid >> 2;                              // 0..127
  const int sBcol = ((tid & 3) ^ ((sBrow >> 2) & 3)) * 8;

  const u16* gA = A + (size_t)(row0 + sArow) * lda + sAcol;
  const u16* gB = B + (size_t)(col0 + sBrow) * ldb + sBcol;
  const size_t a64 = (size_t)64 * lda;
  const size_t b128 = (size_t)128 * ldb;

#define STAGE_A(buf, h, kt)                                          \
  do {                                                               \
    const u16* _g = gA + (size_t)(h) * 128 * lda + (size_t)(kt) * 64;\
    u16* _l = &As[buf][h][0] + tid * 8;                              \
    GLD(_g, _l);                                                     \
    GLD(_g + a64, _l + 4096);                                        \
  } while (0)
#define STAGE_B(buf, kk, kt)                                         \
  do {                                                               \
    const u16* _g = gB + (size_t)(kt) * 64 + (kk) * 32;              \
    u16* _l = &Bs[buf][kk][0] + tid * 8;                             \
    GLD(_g, _l);                                                     \
    GLD(_g + b128, _l + 4096);                                       \
  } while (0)

  // fragment read offsets (u16), swizzle-aware. Read rows: A r = m*16+fr (m even*16 ->
  // (r>>1)&7 == (fr>>1)&7); B r = wc*64+n*16+fr -> (r>>2)&3 == (fr>>2)&3.
  const int fr = l & 15;
  const int g8 = (l >> 4) * 8;                     // 16B slot * 8 u16
  const int acp0 = g8 ^ (((fr >> 1) & 7) * 8);     // A kk0
  const int acp1 = (32 + g8) ^ (((fr >> 1) & 7) * 8);  // A kk1 (slots 4..7)
  const int bcp = g8 ^ (((fr >> 2) & 3) * 8);      // B within 64B row

#define RA(buf, m, cp) (*(const bf16x8*)(&As[buf][wr][((m) * 16 + fr) * 64 + (cp)]))
#define RB(buf, n, kk) (*(const bf16x8*)(&Bs[buf][kk][(wc * 64 + (n) * 16 + fr) * 32 + bcp]))

  f32x4 acc[8][4] = {};
  bf16x8 a0[8], a1[8], bb0, bb1;

  const int nkt = K >> 6;  // >= 2, even
  const int nit = nkt >> 1;

  // prologue: t0 fully (4 halves), then t1.Bk0, t1.Ah0 (rota supplies t1.Ah1@p1, t1.Bk1@p2)
  STAGE_A(0, 0, 0); STAGE_A(0, 1, 0);
  STAGE_B(0, 0, 0); STAGE_B(0, 1, 0);
  STAGE_B(1, 0, 1); STAGE_A(1, 0, 1);
  asm volatile("s_waitcnt vmcnt(4)"); DSB();
  SBAR();

  for (int i = 0; i < nit; ++i) {
    const int u = 2 * i + 1;
    const int v = (2 * i + 2 < nkt) ? 2 * i + 2 : nkt - 1;
    const int w2 = (2 * i + 3 < nkt) ? 2 * i + 3 : nkt - 1;

    // ---- p1: t(kk0,n01); stage u.Ah1 ----
#pragma unroll
    for (int m = 0; m < 8; ++m) a0[m] = RA(0, m, acp0);
    bb0 = RB(0, 0, 0); bb1 = RB(0, 1, 0);
    STAGE_A(1, 1, u);
    SBAR();
    asm volatile("s_waitcnt lgkmcnt(0)"); DSB();
    __builtin_amdgcn_s_setprio(1);
    mfma16<0, 1>(acc, a0, bb0, bb1);
    __builtin_amdgcn_s_setprio(0);
    SBAR();
    // ---- p2: t(kk0,n23); stage u.Bk1; vmcnt(6) ----
    bb0 = RB(0, 2, 0); bb1 = RB(0, 3, 0);
    STAGE_B(1, 1, u);
    asm volatile("s_waitcnt vmcnt(6)"); DSB();
    SBAR();
    asm volatile("s_waitcnt lgkmcnt(0)"); DSB();
    __builtin_amdgcn_s_setprio(1);
    mfma16<2, 3>(acc, a0, bb0, bb1);
    __builtin_amdgcn_s_setprio(0);
    SBAR();
    // ---- p3: t(kk1,n01); stage v.Bk0 ----
#pragma unroll
    for (int m = 0; m < 8; ++m) a1[m] = RA(0, m, acp1);
    bb0 = RB(0, 0, 1); bb1 = RB(0, 1, 1);
    STAGE_B(0, 0, v);
    SBAR();
    asm volatile("s_waitcnt lgkmcnt(0)"); DSB();
    __builtin_amdgcn_s_setprio(1);
    mfma16<0, 1>(acc, a1, bb0, bb1);
    __builtin_amdgcn_s_setprio(0);
    SBAR();
    // ---- p4: t(kk1,n23); stage v.Ah0; vmcnt(6) ----
    bb0 = RB(0, 2, 1); bb1 = RB(0, 3, 1);
    STAGE_A(0, 0, v);
    asm volatile("s_waitcnt vmcnt(6)"); DSB();
    SBAR();
    asm volatile("s_waitcnt lgkmcnt(0)"); DSB();
    __builtin_amdgcn_s_setprio(1);
    mfma16<2, 3>(acc, a1, bb0, bb1);
    __builtin_amdgcn_s_setprio(0);
    SBAR();
    // ---- p5: u(kk0,n01); stage v.Ah1 ----
#pragma unroll
    for (int m = 0; m < 8; ++m) a0[m] = RA(1, m, acp0);
    bb0 = RB(1, 0, 0); bb1 = RB(1, 1, 0);
    STAGE_A(0, 1, v);
    SBAR();
    asm volatile("s_waitcnt lgkmcnt(0)"); DSB();
    __builtin_amdgcn_s_setprio(1);
    mfma16<0, 1>(acc, a0, bb0, bb1);
    __builtin_amdgcn_s_setprio(0);
    SBAR();
    // ---- p6: u(kk0,n23); stage v.Bk1; vmcnt(6) ----
    bb0 = RB(1, 2, 0); bb1 = RB(1, 3, 0);
    STAGE_B(0, 1, v);
    asm volatile("s_waitcnt vmcnt(6)"); DSB();
    SBAR();
    asm volatile("s_waitcnt lgkmcnt(0)"); DSB();
    __builtin_amdgcn_s_setprio(1);
    mfma16<2, 3>(acc, a0, bb0, bb1);
    __builtin_amdgcn_s_setprio(0);
    SBAR();
    // ---- p7: u(kk1,n01); stage w.Bk0 ----
#pragma unroll
    for (int m = 0; m < 8; ++m) a1[m] = RA(1, m, acp1);
    bb0 = RB(1, 0, 1); bb1 = RB(1, 1, 1);
    STAGE_B(1, 0, w2);
    SBAR();
    asm volatile("s_waitcnt lgkmcnt(0)"); DSB();
    __builtin_amdgcn_s_setprio(1);
    mfma16<0, 1>(acc, a1, bb0, bb1);
    __builtin_amdgcn_s_setprio(0);
    SBAR();
    // ---- p8: u(kk1,n23); stage w.Ah0; vmcnt(6) ----
    bb0 = RB(1, 2, 1); bb1 = RB(1, 3, 1);
    STAGE_A(1, 0, w2);
    asm volatile("s_waitcnt vmcnt(6)"); DSB();
    SBAR();
    asm volatile("s_waitcnt lgkmcnt(0)"); DSB();
    __builtin_amdgcn_s_setprio(1);
    mfma16<2, 3>(acc, a1, bb0, bb1);
    __builtin_amdgcn_s_setprio(0);
    SBAR();
  }

  // drain in-flight LDS-DMA before teardown
  asm volatile("s_waitcnt vmcnt(0)"); DSB();

  // epilogue
  const int er = row0 + wr * 128 + ((l >> 4) << 2);
  const int ec = col0 + wc * 64 + (l & 15);
#pragma unroll
  for (int m = 0; m < 8; ++m) {
#pragma unroll
    for (int n = 0; n < 4; ++n) {
      f32x4 vv = acc[m][n];
      const int c = ec + n * 16;
      float bv = bias ? bias[c] : 0.0f;
#pragma unroll
      for (int i = 0; i < 4; ++i) {
        const int r = er + m * 16 + i;
        float x = vv[i] + bv;
        if (relu) x = fmaxf(x, 0.0f);
        if (Cf) Cf[(size_t)r * ldc + c] = x;
        if (Ch) Ch[(size_t)r * ldc + c] = f2bf(x);
      }
    }
  }
#undef STAGE_A
#undef STAGE_B
#undef RA
#undef RB
}

extern "C" void kernel_launch(void* const* d_in, const int* in_sizes, int n_in,
                              void* d_out, int out_size, void* d_ws, size_t ws_size,
                              hipStream_t stream) {
  const int* ids = (const int*)d_in[0];
  const float* tab = (const float*)d_in[1];
  const float* WQ = (const float*)d_in[2];
  const float* WK = (const float*)d_in[3];
  const float* WV = (const float*)d_in[4];
  const float* Wo = (const float*)d_in[5];
  const float* bo = (const float*)d_in[6];
  const float* W1 = (const float*)d_in[7];
  const float* b1 = (const float*)d_in[8];
  const float* W2 = (const float*)d_in[9];
  const float* b2 = (const float*)d_in[10];
  const float* g1 = (const float*)d_in[11];
  const float* be1 = (const float*)d_in[12];
  const float* g2 = (const float*)d_in[13];
  const float* be2 = (const float*)d_in[14];
  const float* Wd = (const float*)d_in[15];
  const float* bd = (const float*)d_in[16];
  float* logits = (float*)d_out;

  if (ws_size < 280000000ull) return;  // need ~276 MB scratch

  char* p = (char*)d_ws;
  auto alloc = [&](size_t bytes) {
    char* r = p;
    p += (bytes + 255) & ~(size_t)255;
    return r;
  };
  float* embf = (float*)alloc((size_t)NT * DM * 4);
  u16* embh = (u16*)alloc((size_t)NT * DM * 2);
  u16* WQh = (u16*)alloc((size_t)DM * DM * 2);
  u16* WKh = (u16*)alloc((size_t)DM * DM * 2);
  u16* WVh = (u16*)alloc((size_t)DM * DM * 2);
  u16* Woh = (u16*)alloc((size_t)DM * DM * 2);
  u16* W1h = (u16*)alloc((size_t)HD * DM * 2);
  u16* W2h = (u16*)alloc((size_t)DM * HD * 2);
  u16* Wdh = (u16*)alloc((size_t)NV * DM * 2);
  u16* Qh = (u16*)alloc((size_t)NT * DM * 2);
  u16* Kh = (u16*)alloc((size_t)NT * DM * 2);
  u16* VTh = (u16*)alloc((size_t)NBATCH * DM * SEQ * 2);
  float* scoresf = (float*)alloc((size_t)NBATCH * SEQ * SEQ * 4);
  u16* Ph = (u16*)alloc((size_t)NBATCH * SEQ * SEQ * 2);
  u16* zh = (u16*)alloc((size_t)NT * DM * 2);
  float* r1f = (float*)alloc((size_t)NT * DM * 4);
  float* xf = (float*)alloc((size_t)NT * DM * 4);
  u16* xh = (u16*)alloc((size_t)NT * DM * 2);
  u16* hh = (u16*)alloc((size_t)NT * HD * 2);
  float* r2f = (float*)alloc((size_t)NT * DM * 4);
  u16* outh = (u16*)alloc((size_t)NT * DM * 2);

  // --- weight casts to bf16 ---
  cast_bf16_kernel<<<dim3(DM * DM / 8 / 256), 256, 0, stream>>>(WQ, WQh, DM * DM / 8);
  cast_bf16_kernel<<<dim3(DM * DM / 8 / 256), 256, 0, stream>>>(WK, WKh, DM * DM / 8);
  cast_bf16_kernel<<<dim3(DM * DM / 8 / 256), 256, 0, stream>>>(WV, WVh, DM * DM / 8);
  cast_bf16_kernel<<<dim3(DM * DM / 8 / 256), 256, 0, stream>>>(Wo, Woh, DM * DM / 8);
  cast_bf16_kernel<<<dim3(HD * DM / 8 / 256), 256, 0, stream>>>(W1, W1h, HD * DM / 8);
  cast_bf16_kernel<<<dim3(DM * HD / 8 / 256), 256, 0, stream>>>(W2, W2h, DM * HD / 8);
  cast_bf16_kernel<<<dim3(NV * DM / 8 / 256), 256, 0, stream>>>(Wd, Wdh, NV * DM / 8);

  // --- embedding ---
  embed_kernel<<<NT, 256, 0, stream>>>(ids, tab, embf, embh);

  // --- Q, K projections (token layout [NT, DM]) ---
  gemm_bt<<<dim3(DM / BN, NT / BM, 1), 256, 0, stream>>>(
      embh, WQh, nullptr, Qh, nullptr, nullptr, DM, DM, DM, DM, 0, 0, 0, 0);
  gemm_bt<<<dim3(DM / BN, NT / BM, 1), 256, 0, stream>>>(
      embh, WKh, nullptr, Kh, nullptr, nullptr, DM, DM, DM, DM, 0, 0, 0, 0);

  // --- V^T per batch: VT[b][e][s] = sum_d WV[e,d] * emb[s,b,d] ---
  gemm_bt<<<dim3(SEQ / BN, DM / BM, NBATCH), 256, 0, stream>>>(
      WVh, embh, nullptr, VTh, nullptr, nullptr, DM, DM, NBATCH * DM, SEQ,
      0, DM, (long)DM * SEQ, 0);

  // --- scores[b][q][k] = Q_b . K_b (scale folded into softmax) ---
  gemm_bt<<<dim3(SEQ / BN, SEQ / BM, NBATCH), 256, 0, stream>>>(
      Qh, Kh, scoresf, nullptr, nullptr, nullptr, DM, NBATCH * DM, NBATCH * DM, SEQ,
      DM, DM, (long)SEQ * SEQ, 0);

  softmax_kernel<<<NBATCH * SEQ, 256, 0, stream>>>(scoresf, Ph);

  // --- Z[b][q][d] = sum_k P[b,q,k] * VT[b,d,k], written to token layout zh ---
  gemm_bt<<<dim3(DM / BN, SEQ / BM, NBATCH), 256, 0, stream>>>(
      Ph, VTh, nullptr, zh, nullptr, nullptr, SEQ, SEQ, SEQ, NBATCH * DM,
      (long)SEQ * SEQ, (long)DM * SEQ, DM, 0);

  // --- r1 = z @ Wo^T + bo + emb ---
  gemm_bt<<<dim3(DM / BN, NT / BM, 1), 256, 0, stream>>>(
      zh, Woh, r1f, nullptr, bo, embf, DM, DM, DM, DM, 0, 0, 0, 0);

  ln_kernel<<<NT, 256, 0, stream>>>(r1f, g1, be1, xf, xh);

  // --- FFN1: 256x256 8-phase v3 (grid 16x16 = 256 blocks) ---
  gemm256_bt<<<dim3((NT / 256) * (HD / 256)), 512, 0, stream>>>(
      xh, W1h, nullptr, hh, b1, DM, DM, DM, HD, NT / 256, HD / 256, 1);
  // --- FFN2 (keep m97) ---
  gemm_bt<<<dim3(DM / BN, NT / BM, 1), 256, 0, stream>>>(
      hh, W2h, r2f, nullptr, b2, xf, HD, HD, HD, DM, 0, 0, 0, 0);

  ln_kernel<<<NT, 256, 0, stream>>>(r2f, g2, be2, nullptr, outh);

  // --- logits: 256x256 8-phase v3 (grid 16x125 = 2000 blocks) ---
  gemm256_bt<<<dim3((NT / 256) * (NV / 256)), 512, 0, stream>>>(
      outh, Wdh, logits, nullptr, bd, DM, DM, DM, NV, NT / 256, NV / 256, 0);
}